// Round 8
// baseline (8553.709 us; speedup 1.0000x reference)
//
#include <hip/hip_runtime.h>

typedef __bf16 bf16x8 __attribute__((ext_vector_type(8)));
typedef float f32x4 __attribute__((ext_vector_type(4)));
typedef unsigned short u16;
typedef unsigned int u32;

#define T_ 64
#define B_ 1024
#define H_ 1024
#define G4_ 4096
#define HB_ (B_ * H_)
#define CHUNK_ 16
#define NBLK_ 512
#define PARTSZ_ (B_ * 2 * 64)

__device__ inline u16 f2bf(float f) {
  u32 u = __float_as_uint(f);
  u32 r = (u + 0x7fffu + ((u >> 16) & 1u)) >> 16;  // RNE
  return (u16)r;
}

__device__ inline uint2 cvt4(float4 v) {
  uint2 r;
  r.x = (u32)f2bf(v.x) | ((u32)f2bf(v.y) << 16);
  r.y = (u32)f2bf(v.z) | ((u32)f2bf(v.w) << 16);
  return r;
}

__device__ __forceinline__ void gload16(const void* g, void* l) {
  __builtin_amdgcn_global_load_lds(
      (const __attribute__((address_space(1))) unsigned int*)g,
      (__attribute__((address_space(3))) unsigned int*)l, 16, 0, 0);
}

__device__ inline float fsig(float x) { return 1.f / (1.f + __expf(-x)); }
__device__ inline float ftanh(float x) {
  float e = __expf(2.f * x);
  return 1.f - 2.f / (e + 1.f);
}

// ---------- prep: WihP/WhhP gate-interleaved-row bf16 [4096][1024], bcP permuted bias,
// hb0=bf16(h0), bar[64]=0.  Permutation: n' = (j>>4)*64 + gate*16 + (j&15)
__global__ void prep_kernel(const float* __restrict__ W_ih, const float* __restrict__ W_hh,
                            const float* __restrict__ b_ih, const float* __restrict__ b_hh,
                            const float* __restrict__ h0,
                            u16* __restrict__ WihP, u16* __restrict__ WhhP,
                            float* __restrict__ bcP, u16* __restrict__ hb0,
                            u32* __restrict__ bar) {
  int bid = blockIdx.x, tid = threadIdx.x;
  if (bid < 4096) {
    int np = bid;
    int gate = (np >> 4) & 3;
    int j = ((np >> 6) << 4) | (np & 15);
    size_t srow = (size_t)(gate * 1024 + j) * 1024;
    int base = tid << 2;
    *(uint2*)(WihP + (size_t)np * 1024 + base) = cvt4(*(const float4*)(W_ih + srow + base));
    *(uint2*)(WhhP + (size_t)np * 1024 + base) = cvt4(*(const float4*)(W_hh + srow + base));
  } else if (bid < 5120) {
    int i = ((bid - 4096) * 256 + tid) << 2;
    *(uint2*)(hb0 + i) = cvt4(*(const float4*)(h0 + i));
  } else {
#pragma unroll
    for (int q = 0; q < 16; ++q) {
      int np = q * 256 + tid;
      int gate = (np >> 4) & 3;
      int j = ((np >> 6) << 4) | (np & 15);
      int srcn = gate * 1024 + j;
      bcP[np] = b_ih[srcn] + b_hh[srcn];
    }
    if (tid < T_) bar[tid] = 0;  // per-step barrier counters
  }
}

// ---------- gather ALL 64 steps: XEall[t][b][:] = bf16(emb[x[b,t]])
__global__ void gather_kernel(const int* __restrict__ x, const float* __restrict__ emb,
                              u16* __restrict__ XEall) {
  int b = blockIdx.x, tc = blockIdx.y;
  int row = x[b * T_ + tc];
  int e = threadIdx.x << 2;
  float4 v = *(const float4*)(emb + (size_t)row * H_ + e);
  *(uint2*)(XEall + ((size_t)tc * B_ + b) * H_ + e) = cvt4(v);
}

// ---------- x-projection big GEMM (128x128, 4 waves of 64x64, BK=64, single LDS buf):
// GXc[gm][n'] = bf16( XEc[gm].WihP[n'] + bcP[n'] ),  M = 16*1024, N = 4096, K = 1024.
// XCD mapping: per XCD, 4 m-groups of 4 m-tiles (1MB XE L2-resident), n-inner sweep.
__global__ void __launch_bounds__(256, 2) xproj_kernel(
    const u16* __restrict__ XEc, const u16* __restrict__ WihP,
    const float* __restrict__ bcP, u16* __restrict__ GXc) {
  __shared__ char smem[32768];  // lsA [128][128B] + lsB [128][128B]
  const int tid = threadIdx.x;
  const int lane = tid & 63;
  const int wave = tid >> 6;
  const int wm = wave >> 1, wn = wave & 1;
  const int hbid = blockIdx.x;  // 4096 = 8 XCD x 512
  const int xcd = hbid & 7;
  const int s9 = hbid >> 3;           // [0,512)
  const int mg = s9 >> 7;             // 4 m-groups
  const int rem = s9 & 127;
  const int n0 = (rem >> 2) * 128;    // 32 n-tiles, inner sweep
  const int m0 = (xcd * 16 + mg * 4 + (rem & 3)) * 128;

  const u16* srcA[4];
  const u16* srcB[4];
  int betaA[4], betaB[4];
#pragma unroll
  for (int s = 0; s < 4; ++s) {
    int beta = (s * 256 + tid) * 16;             // 0..16K
    int row = beta >> 7;                         // 128B rows
    int colu = (beta & 127) ^ ((row & 7) << 4);  // pre-swizzled source col
    int kl = colu >> 1;
    srcA[s] = XEc + (size_t)(m0 + row) * 1024 + kl;
    srcB[s] = WihP + (size_t)(n0 + row) * 1024 + kl;
    betaA[s] = beta;
    betaB[s] = 16384 + beta;
  }

  f32x4 acc[4][4] = {};
  const int rsel = lane & 15;
  const int ksel = (lane >> 4) << 4;

  for (int kt = 0; kt < 16; ++kt) {
#pragma unroll
    for (int s = 0; s < 4; ++s) gload16(srcA[s], smem + betaA[s]);
#pragma unroll
    for (int s = 0; s < 4; ++s) gload16(srcB[s], smem + betaB[s]);
#pragma unroll
    for (int s = 0; s < 4; ++s) { srcA[s] += 64; srcB[s] += 64; }
    __syncthreads();
#pragma unroll
    for (int kk = 0; kk < 2; ++kk) {
      const int colb = kk * 64 + ksel;
      bf16x8 af[4], bfr[4];
#pragma unroll
      for (int mi = 0; mi < 4; ++mi) {
        int row = wm * 64 + mi * 16 + rsel;
        af[mi] = *(const bf16x8*)(smem + row * 128 + (colb ^ ((row & 7) << 4)));
      }
#pragma unroll
      for (int ni = 0; ni < 4; ++ni) {
        int row = wn * 64 + ni * 16 + rsel;
        bfr[ni] = *(const bf16x8*)(smem + 16384 + row * 128 + (colb ^ ((row & 7) << 4)));
      }
#pragma unroll
      for (int mi = 0; mi < 4; ++mi)
#pragma unroll
        for (int ni = 0; ni < 4; ++ni)
          acc[mi][ni] = __builtin_amdgcn_mfma_f32_16x16x32_bf16(af[mi], bfr[ni], acc[mi][ni], 0, 0, 0);
    }
    __syncthreads();
  }

  const int rbase = (lane >> 4) << 2;
  const int cbase = lane & 15;
  float bc[4];
#pragma unroll
  for (int ni = 0; ni < 4; ++ni) bc[ni] = bcP[n0 + wn * 64 + ni * 16 + cbase];
#pragma unroll
  for (int mi = 0; mi < 4; ++mi) {
#pragma unroll
    for (int ni = 0; ni < 4; ++ni) {
      int gc = n0 + wn * 64 + ni * 16 + cbase;
#pragma unroll
      for (int r = 0; r < 4; ++r) {
        int gm = m0 + wm * 64 + mi * 16 + rbase + r;
        GXc[(size_t)gm * G4_ + gc] = f2bf(acc[mi][ni][r] + bc[ni]);
      }
    }
  }
}

// ---------- persistent recurrent kernel: all 64 steps, manual per-step grid barrier.
// Co-residency by resource math: 512 blocks, 64KB LDS -> exactly 2 blocks/CU x 256 CU.
// Per step: gates = GX(t)[LDS] + hb @ WhhP^T; c in REGISTERS across steps.
__global__ void __launch_bounds__(256, 2) rec_kernel(
    u16* __restrict__ hbD, const u16* __restrict__ WhhP,
    const u16* __restrict__ GXall, const float* __restrict__ c0,
    float* __restrict__ part, const float* __restrict__ Wout,
    const float* __restrict__ bout, float* __restrict__ out,
    u32* __restrict__ bar) {
  __shared__ char smem[65536];  // A dbuf 2x16K | B dbuf 2x8K @32768 | GX 16K @49152
  const int tid = threadIdx.x;
  const int lane = tid & 63;
  const int qm = tid >> 6;  // wave = m-slice [0,4)
  const int hbid = blockIdx.x;
  const int L = (hbid & 7) * 64 + (hbid >> 3);  // XCD swizzle: W n-slice per XCD
  const int bx = L >> 3;   // [0,64): n-tile
  const int by = L & 7;    // [0,8): m-tile
  const int n0 = bx * 64;
  const int m0 = by * 128;

  int offA[4], offGX[4], betaS[4];
  int offB[2];
#pragma unroll
  for (int s = 0; s < 4; ++s) {
    int beta = (s * 256 + tid) * 16;             // 0..16K
    int row = beta >> 7;
    int colu = (beta & 127) ^ ((row & 7) << 4);
    offA[s] = (m0 + row) * 1024 + (colu >> 1);
    offGX[s] = (m0 + row) * G4_ + n0 + (colu >> 1);
    betaS[s] = beta;
  }
#pragma unroll
  for (int s = 0; s < 2; ++s) {
    int beta = (s * 256 + tid) * 16;             // 0..8K
    int row = beta >> 7;
    int colu = (beta & 127) ^ ((row & 7) << 4);
    offB[s] = (n0 + row) * 1024 + (colu >> 1);
  }

  const int rsel = lane & 15;
  const int ksel = (lane >> 4) << 4;
  const int rbase = (lane >> 4) << 2;
  const int cbase = lane & 15;
  const int j = bx * 16 + cbase;
  const float w0 = Wout[j], w1 = Wout[1024 + j];

  // cell state lives in registers for the whole sequence
  float creg[2][4];
#pragma unroll
  for (int mi = 0; mi < 2; ++mi)
#pragma unroll
    for (int r = 0; r < 4; ++r)
      creg[mi][r] = c0[(size_t)(m0 + qm * 32 + mi * 16 + rbase + r) * H_ + j];

#pragma unroll 1
  for (int t = 0; t < T_; ++t) {
    const u16* GXt = GXall + (size_t)t * B_ * G4_;
    // GX prefetch: producer (xproj) completed before this kernel launched, so this
    // is barrier-independent; overlaps HBM latency with the barrier wait.
#pragma unroll
    for (int s = 0; s < 4; ++s) gload16(GXt + offGX[s], smem + 49152 + betaS[s]);

    if (t) {
      // ---- grid barrier: wait until all 512 blocks finished step t-1
      if (tid == 0) {
        int guard = 0;
        while (__hip_atomic_load(bar + (t - 1), __ATOMIC_ACQUIRE,
                                 __HIP_MEMORY_SCOPE_AGENT) != NBLK_) {
          __builtin_amdgcn_s_sleep(2);
          if (++guard > (1 << 22)) break;  // bounded: fail loud, never hang
        }
      }
      __syncthreads();
      __builtin_amdgcn_fence(__ATOMIC_ACQUIRE, "agent");

      // finalize previous step's head (partials from all blocks now visible)
      if (by == 0 && tid < 32) {
        int b = bx * 16 + (tid >> 1);
        int cls = tid & 1;
        const float* partR = part + ((t - 1) & 1) * PARTSZ_;
        const float4* pp = (const float4*)(partR + (b << 7) + cls * 64);
        float4 sv = {0.f, 0.f, 0.f, 0.f};
#pragma unroll
        for (int q = 0; q < 16; ++q) {
          float4 v = pp[q];
          sv.x += v.x; sv.y += v.y; sv.z += v.z; sv.w += v.w;
        }
        float l = sv.x + sv.y + sv.z + sv.w + bout[cls];
        float other = __shfl_xor(l, 1);
        float m = fmaxf(l, other);
        float ls = m + __logf(__expf(l - m) + __expf(other - m));
        out[(size_t)(t - 1) * (B_ * 2) + b * 2 + cls] = l - ls;
      }
    }

    const u16* hbR = hbD + (size_t)(t & 1) * HB_;
    u16* hbW = hbD + (size_t)((t + 1) & 1) * HB_;

    // prologue: tile 0 -> buf0
#pragma unroll
    for (int s = 0; s < 4; ++s) gload16(hbR + offA[s], smem + betaS[s]);
#pragma unroll
    for (int s = 0; s < 2; ++s) gload16(WhhP + offB[s], smem + 32768 + betaS[s]);

    f32x4 acc[2][4] = {};
#pragma unroll
    for (int kt = 0; kt < 16; ++kt) {
      const int cur = kt & 1;
      const int abase = cur * 16384;
      const int bbase = 32768 + cur * 8192;
      if (kt < 15) {
        const int nab = (cur ^ 1) * 16384;
        const int nbb = 32768 + (cur ^ 1) * 8192;
        const int kadv = (kt + 1) * 64;
#pragma unroll
        for (int s = 0; s < 4; ++s) gload16(hbR + offA[s] + kadv, smem + nab + betaS[s]);
#pragma unroll
        for (int s = 0; s < 2; ++s) gload16(WhhP + offB[s] + kadv, smem + nbb + betaS[s]);
        asm volatile("s_waitcnt vmcnt(6)" ::: "memory");
      } else {
        asm volatile("s_waitcnt vmcnt(0)" ::: "memory");
      }
      __builtin_amdgcn_s_barrier();
      __builtin_amdgcn_sched_barrier(0);
#pragma unroll
      for (int kk = 0; kk < 2; ++kk) {
        const int colb = kk * 64 + ksel;
        bf16x8 af[2], bfr[4];
#pragma unroll
        for (int mi = 0; mi < 2; ++mi) {
          int row = qm * 32 + mi * 16 + rsel;
          af[mi] = *(const bf16x8*)(smem + abase + row * 128 + (colb ^ ((row & 7) << 4)));
        }
#pragma unroll
        for (int ni = 0; ni < 4; ++ni) {
          int row = ni * 16 + rsel;
          bfr[ni] = *(const bf16x8*)(smem + bbase + row * 128 + (colb ^ ((row & 7) << 4)));
        }
#pragma unroll
        for (int mi = 0; mi < 2; ++mi)
#pragma unroll
          for (int ni = 0; ni < 4; ++ni)
            acc[mi][ni] = __builtin_amdgcn_mfma_f32_16x16x32_bf16(af[mi], bfr[ni], acc[mi][ni], 0, 0, 0);
      }
      __builtin_amdgcn_s_barrier();
      __builtin_amdgcn_sched_barrier(0);
    }

    // epilogue: gates = acc + GX(LDS); cell on register c; head partials (64-slot layout)
    const char* lsGX = smem + 49152;
    float* partW = part + (t & 1) * PARTSZ_;
#pragma unroll
    for (int mi = 0; mi < 2; ++mi) {
#pragma unroll
      for (int r = 0; r < 4; ++r) {
        int grow = qm * 32 + mi * 16 + rbase + r;  // row within 128-tile
        int b = m0 + grow;
        int gxswz = (grow & 7) << 4;
        float gx0 = __uint_as_float(
            (u32)*(const u16*)(lsGX + ((grow << 7) | ((cbase << 1) ^ gxswz))) << 16);
        float gx1 = __uint_as_float(
            (u32)*(const u16*)(lsGX + ((grow << 7) | ((((16 + cbase) << 1)) ^ gxswz))) << 16);
        float gx2 = __uint_as_float(
            (u32)*(const u16*)(lsGX + ((grow << 7) | ((((32 + cbase) << 1)) ^ gxswz))) << 16);
        float gx3 = __uint_as_float(
            (u32)*(const u16*)(lsGX + ((grow << 7) | ((((48 + cbase) << 1)) ^ gxswz))) << 16);
        float gi = acc[mi][0][r] + gx0;
        float gf = acc[mi][1][r] + gx1;
        float gg = acc[mi][2][r] + gx2;
        float go = acc[mi][3][r] + gx3;
        float c2 = fsig(gf) * creg[mi][r] + fsig(gi) * ftanh(gg);
        float h2 = fsig(go) * ftanh(c2);
        creg[mi][r] = c2;
        hbW[(size_t)b * H_ + j] = f2bf(h2);
        float p0 = c2 * w0, p1 = c2 * w1;
#pragma unroll
        for (int off = 1; off < 16; off <<= 1) {
          p0 += __shfl_xor(p0, off);
          p1 += __shfl_xor(p1, off);
        }
        if (cbase == 0) {
          partW[(b << 7) + bx] = p0;
          partW[(b << 7) + 64 + bx] = p1;
        }
      }
    }

    // ---- signal completion of step t (release: make hbW/part/out stores visible)
    __builtin_amdgcn_fence(__ATOMIC_RELEASE, "agent");
    __syncthreads();
    if (tid == 0)
      __hip_atomic_fetch_add(bar + t, 1u, __ATOMIC_RELEASE, __HIP_MEMORY_SCOPE_AGENT);
  }
}

// ---------- final: reduce step-63 partials -> out[63] (log-softmax) + out_final (raw)
__global__ void final_kernel(const float* __restrict__ partR, const float* __restrict__ bout,
                             float* __restrict__ out) {
  int gid = blockIdx.x * 256 + threadIdx.x;  // 2048 = 1024 b x 2 cls
  int b = gid >> 1, cls = gid & 1;
  const float4* pp = (const float4*)(partR + (b << 7) + cls * 64);
  float4 sv = {0.f, 0.f, 0.f, 0.f};
#pragma unroll
  for (int q = 0; q < 16; ++q) {
    float4 v = pp[q];
    sv.x += v.x; sv.y += v.y; sv.z += v.z; sv.w += v.w;
  }
  float l = sv.x + sv.y + sv.z + sv.w + bout[cls];
  out[(size_t)T_ * (B_ * 2) + b * 2 + cls] = l;  // out_final raw
  float other = __shfl_xor(l, 1);
  float m = fmaxf(l, other);
  float ls = m + __logf(__expf(l - m) + __expf(other - m));
  out[(size_t)63 * (B_ * 2) + b * 2 + cls] = l - ls;
}

extern "C" void kernel_launch(void* const* d_in, const int* in_sizes, int n_in,
                              void* d_out, int out_size, void* d_ws, size_t ws_size,
                              hipStream_t stream) {
  const int* x      = (const int*)d_in[0];
  const float* emb  = (const float*)d_in[1];
  const float* W_ih = (const float*)d_in[2];
  const float* W_hh = (const float*)d_in[3];
  const float* b_ih = (const float*)d_in[4];
  const float* b_hh = (const float*)d_in[5];
  const float* W_out = (const float*)d_in[6];
  const float* b_out = (const float*)d_in[7];
  const float* h0   = (const float*)d_in[8];
  const float* c0   = (const float*)d_in[9];
  float* out = (float*)d_out;

  // workspace (~662 MB; poison fills show ws >= 800 MB)
  char* w = (char*)d_ws;
  u16* WihP = (u16*)w;   w += (size_t)G4_ * H_ * 2;             // 8 MB
  u16* WhhP = (u16*)w;   w += (size_t)G4_ * H_ * 2;             // 8 MB
  u16* XEall = (u16*)w;  w += (size_t)T_ * HB_ * 2;             // 128 MB
  u16* GXall = (u16*)w;  w += (size_t)T_ * B_ * G4_ * 2;        // 512 MB
  u16* hb   = (u16*)w;   w += (size_t)2 * HB_ * 2;              // 4 MB
  float* bcP = (float*)w;  w += (size_t)G4_ * 4;
  float* part = (float*)w; w += (size_t)2 * PARTSZ_ * 4;        // 1 MB (double buffer)
  u32* bar = (u32*)w;      w += (size_t)T_ * 4;                 // per-step counters

  prep_kernel<<<5121, 256, 0, stream>>>(W_ih, W_hh, b_ih, b_hh, h0,
                                        WihP, WhhP, bcP, hb, bar);
  gather_kernel<<<dim3(B_, T_), 256, 0, stream>>>(x, emb, XEall);
  for (int ch = 0; ch < T_ / CHUNK_; ++ch) {
    xproj_kernel<<<4096, 256, 0, stream>>>(XEall + (size_t)ch * CHUNK_ * HB_, WihP, bcP,
                                           GXall + (size_t)ch * CHUNK_ * B_ * G4_);
  }
  rec_kernel<<<NBLK_, 256, 0, stream>>>(hb, WhhP, GXall, c0, part, W_out, b_out, out, bar);
  final_kernel<<<8, 256, 0, stream>>>(part + (63 & 1) * PARTSZ_, b_out, out);
}

// Round 9
// 6262.461 us; speedup vs baseline: 1.3659x; 1.3659x over previous
//
#include <hip/hip_runtime.h>

typedef __bf16 bf16x8 __attribute__((ext_vector_type(8)));
typedef float f32x4 __attribute__((ext_vector_type(4)));
typedef unsigned short u16;
typedef unsigned int u32;

#define T_ 64
#define B_ 1024
#define H_ 1024
#define G4_ 4096
#define HB_ (B_ * H_)
#define CHUNK_ 16
#define NBLK_ 512
#define PARTSZ_ (B_ * 2 * 64)

__device__ inline u16 f2bf(float f) {
  u32 u = __float_as_uint(f);
  u32 r = (u + 0x7fffu + ((u >> 16) & 1u)) >> 16;  // RNE
  return (u16)r;
}

__device__ inline uint2 cvt4(float4 v) {
  uint2 r;
  r.x = (u32)f2bf(v.x) | ((u32)f2bf(v.y) << 16);
  r.y = (u32)f2bf(v.z) | ((u32)f2bf(v.w) << 16);
  return r;
}

__device__ __forceinline__ void gload16(const void* g, void* l) {
  __builtin_amdgcn_global_load_lds(
      (const __attribute__((address_space(1))) unsigned int*)g,
      (__attribute__((address_space(3))) unsigned int*)l, 16, 0, 0);
}

__device__ inline float fsig(float x) { return 1.f / (1.f + __expf(-x)); }
__device__ inline float ftanh(float x) {
  float e = __expf(2.f * x);
  return 1.f - 2.f / (e + 1.f);
}

// ---------- prep: WihP/WhhP gate-interleaved-row bf16 [4096][1024], bcP permuted bias,
// hb0=bf16(h0), flags[64][512]=0.  Permutation: n' = (j>>4)*64 + gate*16 + (j&15)
__global__ void prep_kernel(const float* __restrict__ W_ih, const float* __restrict__ W_hh,
                            const float* __restrict__ b_ih, const float* __restrict__ b_hh,
                            const float* __restrict__ h0,
                            u16* __restrict__ WihP, u16* __restrict__ WhhP,
                            float* __restrict__ bcP, u16* __restrict__ hb0,
                            u32* __restrict__ flags) {
  int bid = blockIdx.x, tid = threadIdx.x;
  if (bid < 4096) {
    int np = bid;
    int gate = (np >> 4) & 3;
    int j = ((np >> 6) << 4) | (np & 15);
    size_t srow = (size_t)(gate * 1024 + j) * 1024;
    int base = tid << 2;
    *(uint2*)(WihP + (size_t)np * 1024 + base) = cvt4(*(const float4*)(W_ih + srow + base));
    *(uint2*)(WhhP + (size_t)np * 1024 + base) = cvt4(*(const float4*)(W_hh + srow + base));
  } else if (bid < 5120) {
    int i = ((bid - 4096) * 256 + tid) << 2;
    *(uint2*)(hb0 + i) = cvt4(*(const float4*)(h0 + i));
  } else if (bid == 5120) {
#pragma unroll
    for (int q = 0; q < 16; ++q) {
      int np = q * 256 + tid;
      int gate = (np >> 4) & 3;
      int j = ((np >> 6) << 4) | (np & 15);
      int srcn = gate * 1024 + j;
      bcP[np] = b_ih[srcn] + b_hh[srcn];
    }
  } else {
    // zero flags: 64 steps x 512 blocks = 32768 u32; 32 blocks x 256 thr x 4 u32
    int idx = ((bid - 5121) * 256 + tid) << 2;
    *(uint4*)(flags + idx) = uint4{0u, 0u, 0u, 0u};
  }
}

// ---------- gather ALL 64 steps: XEall[t][b][:] = bf16(emb[x[b,t]])
__global__ void gather_kernel(const int* __restrict__ x, const float* __restrict__ emb,
                              u16* __restrict__ XEall) {
  int b = blockIdx.x, tc = blockIdx.y;
  int row = x[b * T_ + tc];
  int e = threadIdx.x << 2;
  float4 v = *(const float4*)(emb + (size_t)row * H_ + e);
  *(uint2*)(XEall + ((size_t)tc * B_ + b) * H_ + e) = cvt4(v);
}

// ---------- x-projection big GEMM (128x128, 4 waves of 64x64, BK=64, single LDS buf):
// GXc[gm][n'] = bf16( XEc[gm].WihP[n'] + bcP[n'] ),  M = 16*1024, N = 4096, K = 1024.
__global__ void __launch_bounds__(256, 2) xproj_kernel(
    const u16* __restrict__ XEc, const u16* __restrict__ WihP,
    const float* __restrict__ bcP, u16* __restrict__ GXc) {
  __shared__ char smem[32768];  // lsA [128][128B] + lsB [128][128B]
  const int tid = threadIdx.x;
  const int lane = tid & 63;
  const int wave = tid >> 6;
  const int wm = wave >> 1, wn = wave & 1;
  const int hbid = blockIdx.x;  // 4096 = 8 XCD x 512
  const int xcd = hbid & 7;
  const int s9 = hbid >> 3;           // [0,512)
  const int mg = s9 >> 7;             // 4 m-groups
  const int rem = s9 & 127;
  const int n0 = (rem >> 2) * 128;    // 32 n-tiles, inner sweep
  const int m0 = (xcd * 16 + mg * 4 + (rem & 3)) * 128;

  const u16* srcA[4];
  const u16* srcB[4];
  int betaA[4], betaB[4];
#pragma unroll
  for (int s = 0; s < 4; ++s) {
    int beta = (s * 256 + tid) * 16;             // 0..16K
    int row = beta >> 7;                         // 128B rows
    int colu = (beta & 127) ^ ((row & 7) << 4);  // pre-swizzled source col
    int kl = colu >> 1;
    srcA[s] = XEc + (size_t)(m0 + row) * 1024 + kl;
    srcB[s] = WihP + (size_t)(n0 + row) * 1024 + kl;
    betaA[s] = beta;
    betaB[s] = 16384 + beta;
  }

  f32x4 acc[4][4] = {};
  const int rsel = lane & 15;
  const int ksel = (lane >> 4) << 4;

  for (int kt = 0; kt < 16; ++kt) {
#pragma unroll
    for (int s = 0; s < 4; ++s) gload16(srcA[s], smem + betaA[s]);
#pragma unroll
    for (int s = 0; s < 4; ++s) gload16(srcB[s], smem + betaB[s]);
#pragma unroll
    for (int s = 0; s < 4; ++s) { srcA[s] += 64; srcB[s] += 64; }
    __syncthreads();
#pragma unroll
    for (int kk = 0; kk < 2; ++kk) {
      const int colb = kk * 64 + ksel;
      bf16x8 af[4], bfr[4];
#pragma unroll
      for (int mi = 0; mi < 4; ++mi) {
        int row = wm * 64 + mi * 16 + rsel;
        af[mi] = *(const bf16x8*)(smem + row * 128 + (colb ^ ((row & 7) << 4)));
      }
#pragma unroll
      for (int ni = 0; ni < 4; ++ni) {
        int row = wn * 64 + ni * 16 + rsel;
        bfr[ni] = *(const bf16x8*)(smem + 16384 + row * 128 + (colb ^ ((row & 7) << 4)));
      }
#pragma unroll
      for (int mi = 0; mi < 4; ++mi)
#pragma unroll
        for (int ni = 0; ni < 4; ++ni)
          acc[mi][ni] = __builtin_amdgcn_mfma_f32_16x16x32_bf16(af[mi], bfr[ni], acc[mi][ni], 0, 0, 0);
    }
    __syncthreads();
  }

  const int rbase = (lane >> 4) << 2;
  const int cbase = lane & 15;
  float bc[4];
#pragma unroll
  for (int ni = 0; ni < 4; ++ni) bc[ni] = bcP[n0 + wn * 64 + ni * 16 + cbase];
#pragma unroll
  for (int mi = 0; mi < 4; ++mi) {
#pragma unroll
    for (int ni = 0; ni < 4; ++ni) {
      int gc = n0 + wn * 64 + ni * 16 + cbase;
#pragma unroll
      for (int r = 0; r < 4; ++r) {
        int gm = m0 + wm * 64 + mi * 16 + rbase + r;
        GXc[(size_t)gm * G4_ + gc] = f2bf(acc[mi][ni][r] + bc[ni]);
      }
    }
  }
}

// ---------- persistent recurrent kernel: all 64 steps.
// Per-GROUP barrier: block (bx,by) only needs the 64 blocks with same by (they write
// h rows [by*128, by*128+128)). Flags (1 per block per step), relaxed-load polling
// (no per-poll L2 invalidate), ONE acquire fence per step. Head partials -> per-step
// slab, finalized by a post-kernel. c stays in registers all 64 steps.
__global__ void __launch_bounds__(256, 2) rec_kernel(
    u16* __restrict__ hbD, const u16* __restrict__ WhhP,
    const u16* __restrict__ GXall, const float* __restrict__ c0,
    float* __restrict__ partAll, const float* __restrict__ Wout,
    u32* __restrict__ flags) {
  __shared__ char smem[65536];  // A dbuf 2x16K | B dbuf 2x8K @32768 | GX 16K @49152
  const int tid = threadIdx.x;
  const int lane = tid & 63;
  const int qm = tid >> 6;  // wave = m-slice [0,4)
  const int hbid = blockIdx.x;
  const int L = (hbid & 7) * 64 + (hbid >> 3);  // XCD swizzle: W n-slice per XCD
  const int bx = L >> 3;   // [0,64): n-tile
  const int by = L & 7;    // [0,8): m-tile
  const int n0 = bx * 64;
  const int m0 = by * 128;

  int offA[4], offGX[4], betaS[4];
  int offB[2];
#pragma unroll
  for (int s = 0; s < 4; ++s) {
    int beta = (s * 256 + tid) * 16;             // 0..16K
    int row = beta >> 7;
    int colu = (beta & 127) ^ ((row & 7) << 4);
    offA[s] = (m0 + row) * 1024 + (colu >> 1);
    offGX[s] = (m0 + row) * G4_ + n0 + (colu >> 1);
    betaS[s] = beta;
  }
#pragma unroll
  for (int s = 0; s < 2; ++s) {
    int beta = (s * 256 + tid) * 16;             // 0..8K
    int row = beta >> 7;
    int colu = (beta & 127) ^ ((row & 7) << 4);
    offB[s] = (n0 + row) * 1024 + (colu >> 1);
  }

  const int rsel = lane & 15;
  const int ksel = (lane >> 4) << 4;
  const int rbase = (lane >> 4) << 2;
  const int cbase = lane & 15;
  const int j = bx * 16 + cbase;
  const float w0 = Wout[j], w1 = Wout[1024 + j];

  // cell state lives in registers for the whole sequence
  float creg[2][4];
#pragma unroll
  for (int mi = 0; mi < 2; ++mi)
#pragma unroll
    for (int r = 0; r < 4; ++r)
      creg[mi][r] = c0[(size_t)(m0 + qm * 32 + mi * 16 + rbase + r) * H_ + j];

#pragma unroll 1
  for (int t = 0; t < T_; ++t) {
    const u16* GXt = GXall + (size_t)t * B_ * G4_;
    // GX prefetch (producer finished pre-launch; overlaps the barrier wait).
    // Safe vs lsGX epilogue reads of t-1: trailing __syncthreads of prev iter.
#pragma unroll
    for (int s = 0; s < 4; ++s) gload16(GXt + offGX[s], smem + 49152 + betaS[s]);

    if (t) {
      // ---- group barrier: wait for the 64 blocks of group `by` (they write our h rows).
      // Relaxed polls (no L2 invalidate per poll); lane i watches flag i.
      if (tid < 64) {
        const u32* fg = flags + (size_t)(t - 1) * NBLK_ + by * 64;
        int guard = 0;
        while (true) {
          u32 v = __hip_atomic_load(fg + tid, __ATOMIC_RELAXED, __HIP_MEMORY_SCOPE_AGENT);
          if (__all(v != 0)) break;
          __builtin_amdgcn_s_sleep(8);
          if (++guard > (1 << 14)) break;  // bounded: fail loud, never hang
        }
      }
      __syncthreads();
      __builtin_amdgcn_fence(__ATOMIC_ACQUIRE, "agent");  // one invalidate per step
    }

    const u16* hbR = hbD + (size_t)(t & 1) * HB_;
    u16* hbW = hbD + (size_t)((t + 1) & 1) * HB_;

    // prologue: tile 0 -> buf0
#pragma unroll
    for (int s = 0; s < 4; ++s) gload16(hbR + offA[s], smem + betaS[s]);
#pragma unroll
    for (int s = 0; s < 2; ++s) gload16(WhhP + offB[s], smem + 32768 + betaS[s]);

    f32x4 acc[2][4] = {};
#pragma unroll
    for (int kt = 0; kt < 16; ++kt) {
      const int cur = kt & 1;
      const int abase = cur * 16384;
      const int bbase = 32768 + cur * 8192;
      if (kt < 15) {
        const int nab = (cur ^ 1) * 16384;
        const int nbb = 32768 + (cur ^ 1) * 8192;
        const int kadv = (kt + 1) * 64;
#pragma unroll
        for (int s = 0; s < 4; ++s) gload16(hbR + offA[s] + kadv, smem + nab + betaS[s]);
#pragma unroll
        for (int s = 0; s < 2; ++s) gload16(WhhP + offB[s] + kadv, smem + nbb + betaS[s]);
        asm volatile("s_waitcnt vmcnt(6)" ::: "memory");
      } else {
        asm volatile("s_waitcnt vmcnt(0)" ::: "memory");
      }
      __builtin_amdgcn_s_barrier();
      __builtin_amdgcn_sched_barrier(0);
#pragma unroll
      for (int kk = 0; kk < 2; ++kk) {
        const int colb = kk * 64 + ksel;
        bf16x8 af[2], bfr[4];
#pragma unroll
        for (int mi = 0; mi < 2; ++mi) {
          int row = qm * 32 + mi * 16 + rsel;
          af[mi] = *(const bf16x8*)(smem + abase + row * 128 + (colb ^ ((row & 7) << 4)));
        }
#pragma unroll
        for (int ni = 0; ni < 4; ++ni) {
          int row = ni * 16 + rsel;
          bfr[ni] = *(const bf16x8*)(smem + bbase + row * 128 + (colb ^ ((row & 7) << 4)));
        }
#pragma unroll
        for (int mi = 0; mi < 2; ++mi)
#pragma unroll
          for (int ni = 0; ni < 4; ++ni)
            acc[mi][ni] = __builtin_amdgcn_mfma_f32_16x16x32_bf16(af[mi], bfr[ni], acc[mi][ni], 0, 0, 0);
      }
      __builtin_amdgcn_s_barrier();
      __builtin_amdgcn_sched_barrier(0);
    }

    // epilogue: gates = acc + GX(LDS); cell on register c; head partials (64-slot layout)
    const char* lsGX = smem + 49152;
    float* partW = partAll + (size_t)t * PARTSZ_;
#pragma unroll
    for (int mi = 0; mi < 2; ++mi) {
#pragma unroll
      for (int r = 0; r < 4; ++r) {
        int grow = qm * 32 + mi * 16 + rbase + r;  // row within 128-tile
        int b = m0 + grow;
        int gxswz = (grow & 7) << 4;
        float gx0 = __uint_as_float(
            (u32)*(const u16*)(lsGX + ((grow << 7) | ((cbase << 1) ^ gxswz))) << 16);
        float gx1 = __uint_as_float(
            (u32)*(const u16*)(lsGX + ((grow << 7) | ((((16 + cbase) << 1)) ^ gxswz))) << 16);
        float gx2 = __uint_as_float(
            (u32)*(const u16*)(lsGX + ((grow << 7) | ((((32 + cbase) << 1)) ^ gxswz))) << 16);
        float gx3 = __uint_as_float(
            (u32)*(const u16*)(lsGX + ((grow << 7) | ((((48 + cbase) << 1)) ^ gxswz))) << 16);
        float gi = acc[mi][0][r] + gx0;
        float gf = acc[mi][1][r] + gx1;
        float gg = acc[mi][2][r] + gx2;
        float go = acc[mi][3][r] + gx3;
        float c2 = fsig(gf) * creg[mi][r] + fsig(gi) * ftanh(gg);
        float h2 = fsig(go) * ftanh(c2);
        creg[mi][r] = c2;
        hbW[(size_t)b * H_ + j] = f2bf(h2);
        float p0 = c2 * w0, p1 = c2 * w1;
#pragma unroll
        for (int off = 1; off < 16; off <<= 1) {
          p0 += __shfl_xor(p0, off);
          p1 += __shfl_xor(p1, off);
        }
        if (cbase == 0) {
          partW[(b << 7) + bx] = p0;
          partW[(b << 7) + 64 + bx] = p1;
        }
      }
    }

    // ---- signal: own-wave writeback fence (all waves), then one flag store.
    __builtin_amdgcn_fence(__ATOMIC_RELEASE, "agent");
    __syncthreads();
    if (tid == 0)
      __hip_atomic_store(flags + (size_t)t * NBLK_ + by * 64 + bx, 1u,
                         __ATOMIC_RELAXED, __HIP_MEMORY_SCOPE_AGENT);
  }
}

// ---------- final: reduce ALL steps' partials -> out[t] log-softmax; t=63 also raw out_final
__global__ void final_kernel(const float* __restrict__ partAll, const float* __restrict__ bout,
                             float* __restrict__ out) {
  int gid = blockIdx.x * 256 + threadIdx.x;  // 131072 = 64 t x 1024 b x 2 cls
  int t = gid >> 11;
  int r = gid & 2047;
  int b = r >> 1, cls = r & 1;
  const float4* pp = (const float4*)(partAll + (size_t)t * PARTSZ_ + (b << 7) + cls * 64);
  float4 sv = {0.f, 0.f, 0.f, 0.f};
#pragma unroll
  for (int q = 0; q < 16; ++q) {
    float4 v = pp[q];
    sv.x += v.x; sv.y += v.y; sv.z += v.z; sv.w += v.w;
  }
  float l = sv.x + sv.y + sv.z + sv.w + bout[cls];
  float other = __shfl_xor(l, 1);
  float m = fmaxf(l, other);
  float ls = m + __logf(__expf(l - m) + __expf(other - m));
  out[(size_t)t * (B_ * 2) + b * 2 + cls] = l - ls;
  if (t == 63) out[(size_t)T_ * (B_ * 2) + b * 2 + cls] = l;  // out_final raw
}

extern "C" void kernel_launch(void* const* d_in, const int* in_sizes, int n_in,
                              void* d_out, int out_size, void* d_ws, size_t ws_size,
                              hipStream_t stream) {
  const int* x      = (const int*)d_in[0];
  const float* emb  = (const float*)d_in[1];
  const float* W_ih = (const float*)d_in[2];
  const float* W_hh = (const float*)d_in[3];
  const float* b_ih = (const float*)d_in[4];
  const float* b_hh = (const float*)d_in[5];
  const float* W_out = (const float*)d_in[6];
  const float* b_out = (const float*)d_in[7];
  const float* h0   = (const float*)d_in[8];
  const float* c0   = (const float*)d_in[9];
  float* out = (float*)d_out;

  // workspace (~693 MB; poison fills show ws >= 800 MB)
  char* w = (char*)d_ws;
  u16* WihP = (u16*)w;   w += (size_t)G4_ * H_ * 2;             // 8 MB
  u16* WhhP = (u16*)w;   w += (size_t)G4_ * H_ * 2;             // 8 MB
  u16* XEall = (u16*)w;  w += (size_t)T_ * HB_ * 2;             // 128 MB
  u16* GXall = (u16*)w;  w += (size_t)T_ * B_ * G4_ * 2;        // 512 MB
  u16* hb   = (u16*)w;   w += (size_t)2 * HB_ * 2;              // 4 MB
  float* bcP = (float*)w;     w += (size_t)G4_ * 4;
  float* partAll = (float*)w; w += (size_t)T_ * PARTSZ_ * 4;    // 32 MB (per-step slabs)
  u32* flags = (u32*)w;       w += (size_t)T_ * NBLK_ * 4;      // 128 KB

  prep_kernel<<<5153, 256, 0, stream>>>(W_ih, W_hh, b_ih, b_hh, h0,
                                        WihP, WhhP, bcP, hb, flags);
  gather_kernel<<<dim3(B_, T_), 256, 0, stream>>>(x, emb, XEall);
  for (int ch = 0; ch < T_ / CHUNK_; ++ch) {
    xproj_kernel<<<4096, 256, 0, stream>>>(XEall + (size_t)ch * CHUNK_ * HB_, WihP, bcP,
                                           GXall + (size_t)ch * CHUNK_ * B_ * G4_);
  }
  rec_kernel<<<NBLK_, 256, 0, stream>>>(hb, WhhP, GXall, c0, partAll, W_out, flags);
  final_kernel<<<512, 256, 0, stream>>>(partAll, b_out, out);
}

// Round 10
// 1628.254 us; speedup vs baseline: 5.2533x; 3.8461x over previous
//
#include <hip/hip_runtime.h>

typedef __bf16 bf16x8 __attribute__((ext_vector_type(8)));
typedef float f32x4 __attribute__((ext_vector_type(4)));
typedef unsigned short u16;
typedef unsigned int u32;

#define T_ 64
#define B_ 1024
#define H_ 1024
#define G4_ 4096
#define HB_ (B_ * H_)
#define CHUNK_ 16
#define NBLK_ 512
#define PARTSZ_ (B_ * 2 * 64)

__device__ inline u16 f2bf(float f) {
  u32 u = __float_as_uint(f);
  u32 r = (u + 0x7fffu + ((u >> 16) & 1u)) >> 16;  // RNE
  return (u16)r;
}

__device__ inline uint2 cvt4(float4 v) {
  uint2 r;
  r.x = (u32)f2bf(v.x) | ((u32)f2bf(v.y) << 16);
  r.y = (u32)f2bf(v.z) | ((u32)f2bf(v.w) << 16);
  return r;
}

__device__ __forceinline__ void gload16(const void* g, void* l) {
  __builtin_amdgcn_global_load_lds(
      (const __attribute__((address_space(1))) unsigned int*)g,
      (__attribute__((address_space(3))) unsigned int*)l, 16, 0, 0);
}

// write-through 2B store: data lands at the coherence point (L3), never dirty in L2.
__device__ __forceinline__ void store_wt16(u16* p, u16 v) {
  asm volatile("global_store_short %0, %1, off sc0 sc1" :: "v"(p), "v"((u32)v) : "memory");
}

__device__ inline float fsig(float x) { return 1.f / (1.f + __expf(-x)); }
__device__ inline float ftanh(float x) {
  float e = __expf(2.f * x);
  return 1.f - 2.f / (e + 1.f);
}

// ---------- prep: WihP/WhhP gate-interleaved-row bf16 [4096][1024], bcP permuted bias,
// h0slot=bf16(h0), flags[64][512]=0.  Permutation: n' = (j>>4)*64 + gate*16 + (j&15)
__global__ void prep_kernel(const float* __restrict__ W_ih, const float* __restrict__ W_hh,
                            const float* __restrict__ b_ih, const float* __restrict__ b_hh,
                            const float* __restrict__ h0,
                            u16* __restrict__ WihP, u16* __restrict__ WhhP,
                            float* __restrict__ bcP, u16* __restrict__ h0slot,
                            u32* __restrict__ flags) {
  int bid = blockIdx.x, tid = threadIdx.x;
  if (bid < 4096) {
    int np = bid;
    int gate = (np >> 4) & 3;
    int j = ((np >> 6) << 4) | (np & 15);
    size_t srow = (size_t)(gate * 1024 + j) * 1024;
    int base = tid << 2;
    *(uint2*)(WihP + (size_t)np * 1024 + base) = cvt4(*(const float4*)(W_ih + srow + base));
    *(uint2*)(WhhP + (size_t)np * 1024 + base) = cvt4(*(const float4*)(W_hh + srow + base));
  } else if (bid < 5120) {
    int i = ((bid - 4096) * 256 + tid) << 2;
    *(uint2*)(h0slot + i) = cvt4(*(const float4*)(h0 + i));
  } else if (bid == 5120) {
#pragma unroll
    for (int q = 0; q < 16; ++q) {
      int np = q * 256 + tid;
      int gate = (np >> 4) & 3;
      int j = ((np >> 6) << 4) | (np & 15);
      int srcn = gate * 1024 + j;
      bcP[np] = b_ih[srcn] + b_hh[srcn];
    }
  } else {
    int idx = ((bid - 5121) * 256 + tid) << 2;  // 32 blocks x 1024 u32 = 32768
    *(uint4*)(flags + idx) = uint4{0u, 0u, 0u, 0u};
  }
}

// ---------- gather ALL 64 steps: XEall[t][b][:] = bf16(emb[x[b,t]])
__global__ void gather_kernel(const int* __restrict__ x, const float* __restrict__ emb,
                              u16* __restrict__ XEall) {
  int b = blockIdx.x, tc = blockIdx.y;
  int row = x[b * T_ + tc];
  int e = threadIdx.x << 2;
  float4 v = *(const float4*)(emb + (size_t)row * H_ + e);
  *(uint2*)(XEall + ((size_t)tc * B_ + b) * H_ + e) = cvt4(v);
}

// ---------- x-projection big GEMM (128x128, 4 waves of 64x64, BK=64, single LDS buf):
// GXc[gm][n'] = bf16( XEc[gm].WihP[n'] + bcP[n'] ),  M = 16*1024, N = 4096, K = 1024.
__global__ void __launch_bounds__(256, 2) xproj_kernel(
    const u16* __restrict__ XEc, const u16* __restrict__ WihP,
    const float* __restrict__ bcP, u16* __restrict__ GXc) {
  __shared__ char smem[32768];  // lsA [128][128B] + lsB [128][128B]
  const int tid = threadIdx.x;
  const int lane = tid & 63;
  const int wave = tid >> 6;
  const int wm = wave >> 1, wn = wave & 1;
  const int hbid = blockIdx.x;  // 4096 = 8 XCD x 512
  const int xcd = hbid & 7;
  const int s9 = hbid >> 3;           // [0,512)
  const int mg = s9 >> 7;             // 4 m-groups
  const int rem = s9 & 127;
  const int n0 = (rem >> 2) * 128;    // 32 n-tiles, inner sweep
  const int m0 = (xcd * 16 + mg * 4 + (rem & 3)) * 128;

  const u16* srcA[4];
  const u16* srcB[4];
  int betaA[4], betaB[4];
#pragma unroll
  for (int s = 0; s < 4; ++s) {
    int beta = (s * 256 + tid) * 16;             // 0..16K
    int row = beta >> 7;                         // 128B rows
    int colu = (beta & 127) ^ ((row & 7) << 4);  // pre-swizzled source col
    int kl = colu >> 1;
    srcA[s] = XEc + (size_t)(m0 + row) * 1024 + kl;
    srcB[s] = WihP + (size_t)(n0 + row) * 1024 + kl;
    betaA[s] = beta;
    betaB[s] = 16384 + beta;
  }

  f32x4 acc[4][4] = {};
  const int rsel = lane & 15;
  const int ksel = (lane >> 4) << 4;

  for (int kt = 0; kt < 16; ++kt) {
#pragma unroll
    for (int s = 0; s < 4; ++s) gload16(srcA[s], smem + betaA[s]);
#pragma unroll
    for (int s = 0; s < 4; ++s) gload16(srcB[s], smem + betaB[s]);
#pragma unroll
    for (int s = 0; s < 4; ++s) { srcA[s] += 64; srcB[s] += 64; }
    __syncthreads();
#pragma unroll
    for (int kk = 0; kk < 2; ++kk) {
      const int colb = kk * 64 + ksel;
      bf16x8 af[4], bfr[4];
#pragma unroll
      for (int mi = 0; mi < 4; ++mi) {
        int row = wm * 64 + mi * 16 + rsel;
        af[mi] = *(const bf16x8*)(smem + row * 128 + (colb ^ ((row & 7) << 4)));
      }
#pragma unroll
      for (int ni = 0; ni < 4; ++ni) {
        int row = wn * 64 + ni * 16 + rsel;
        bfr[ni] = *(const bf16x8*)(smem + 16384 + row * 128 + (colb ^ ((row & 7) << 4)));
      }
#pragma unroll
      for (int mi = 0; mi < 4; ++mi)
#pragma unroll
        for (int ni = 0; ni < 4; ++ni)
          acc[mi][ni] = __builtin_amdgcn_mfma_f32_16x16x32_bf16(af[mi], bfr[ni], acc[mi][ni], 0, 0, 0);
    }
    __syncthreads();
  }

  const int rbase = (lane >> 4) << 2;
  const int cbase = lane & 15;
  float bc[4];
#pragma unroll
  for (int ni = 0; ni < 4; ++ni) bc[ni] = bcP[n0 + wn * 64 + ni * 16 + cbase];
#pragma unroll
  for (int mi = 0; mi < 4; ++mi) {
#pragma unroll
    for (int ni = 0; ni < 4; ++ni) {
      int gc = n0 + wn * 64 + ni * 16 + cbase;
#pragma unroll
      for (int r = 0; r < 4; ++r) {
        int gm = m0 + wm * 64 + mi * 16 + rbase + r;
        GXc[(size_t)gm * G4_ + gc] = f2bf(acc[mi][ni][r] + bc[ni]);
      }
    }
  }
}

// ---------- persistent recurrent kernel: all 64 steps, NO fences.
// h is communicated via: write-through stores (sc0 sc1 -> L3) + per-step FRESH buffer
// (ring over the dead XEall region) so the reader's L2 has never cached the address.
// Per-group barrier (64 blocks sharing by) with relaxed flag polls. c in registers.
__global__ void __launch_bounds__(256, 2) rec_kernel(
    const u16* __restrict__ h0slot, u16* __restrict__ hring,
    const u16* __restrict__ WhhP, const u16* __restrict__ GXall,
    const float* __restrict__ c0, float* __restrict__ partAll,
    const float* __restrict__ Wout, u32* __restrict__ flags) {
  __shared__ char smem[65536];  // A dbuf 2x16K | B dbuf 2x8K @32768 | GX 16K @49152
  const int tid = threadIdx.x;
  const int lane = tid & 63;
  const int qm = tid >> 6;  // wave = m-slice [0,4)
  const int hbid = blockIdx.x;
  const int L = (hbid & 7) * 64 + (hbid >> 3);  // XCD swizzle: W n-slice per XCD
  const int bx = L >> 3;   // [0,64): n-tile
  const int by = L & 7;    // [0,8): m-tile
  const int n0 = bx * 64;
  const int m0 = by * 128;

  int offA[4], offGX[4], betaS[4];
  int offB[2];
#pragma unroll
  for (int s = 0; s < 4; ++s) {
    int beta = (s * 256 + tid) * 16;             // 0..16K
    int row = beta >> 7;
    int colu = (beta & 127) ^ ((row & 7) << 4);
    offA[s] = (m0 + row) * 1024 + (colu >> 1);
    offGX[s] = (m0 + row) * G4_ + n0 + (colu >> 1);
    betaS[s] = beta;
  }
#pragma unroll
  for (int s = 0; s < 2; ++s) {
    int beta = (s * 256 + tid) * 16;             // 0..8K
    int row = beta >> 7;
    int colu = (beta & 127) ^ ((row & 7) << 4);
    offB[s] = (n0 + row) * 1024 + (colu >> 1);
  }

  const int rsel = lane & 15;
  const int ksel = (lane >> 4) << 4;
  const int rbase = (lane >> 4) << 2;
  const int cbase = lane & 15;
  const int j = bx * 16 + cbase;
  const float w0 = Wout[j], w1 = Wout[1024 + j];

  // cell state lives in registers for the whole sequence
  float creg[2][4];
#pragma unroll
  for (int mi = 0; mi < 2; ++mi)
#pragma unroll
    for (int r = 0; r < 4; ++r)
      creg[mi][r] = c0[(size_t)(m0 + qm * 32 + mi * 16 + rbase + r) * H_ + j];

#pragma unroll 1
  for (int t = 0; t < T_; ++t) {
    const u16* GXt = GXall + (size_t)t * B_ * G4_;
    // GX prefetch (producer finished pre-launch; overlaps the barrier wait).
#pragma unroll
    for (int s = 0; s < 4; ++s) gload16(GXt + offGX[s], smem + 49152 + betaS[s]);

    if (t) {
      // group barrier: wait for the 64 same-by blocks (they wrote our h rows, step t-1)
      if (tid < 64) {
        const u32* fg = flags + (size_t)(t - 1) * NBLK_ + by * 64;
        int guard = 0;
        while (true) {
          u32 v = __hip_atomic_load(fg + tid, __ATOMIC_RELAXED, __HIP_MEMORY_SCOPE_AGENT);
          if (__all(v != 0)) break;
          __builtin_amdgcn_s_sleep(2);
          if (++guard > (1 << 18)) break;  // bounded: fail loud, never hang
        }
      }
      __syncthreads();  // no acquire fence: h buffer is fresh, L2 never cached it
    }

    // h ring: step t reads hring[t] (t=0 -> h0slot), writes hring[t+1]
    const u16* hbR = t ? (hring + (size_t)(t - 1) * HB_) : h0slot;
    u16* hbW = hring + (size_t)t * HB_;

    // prologue: tile 0 -> buf0
#pragma unroll
    for (int s = 0; s < 4; ++s) gload16(hbR + offA[s], smem + betaS[s]);
#pragma unroll
    for (int s = 0; s < 2; ++s) gload16(WhhP + offB[s], smem + 32768 + betaS[s]);

    f32x4 acc[2][4] = {};
#pragma unroll
    for (int kt = 0; kt < 16; ++kt) {
      const int cur = kt & 1;
      const int abase = cur * 16384;
      const int bbase = 32768 + cur * 8192;
      if (kt < 15) {
        const int nab = (cur ^ 1) * 16384;
        const int nbb = 32768 + (cur ^ 1) * 8192;
        const int kadv = (kt + 1) * 64;
#pragma unroll
        for (int s = 0; s < 4; ++s) gload16(hbR + offA[s] + kadv, smem + nab + betaS[s]);
#pragma unroll
        for (int s = 0; s < 2; ++s) gload16(WhhP + offB[s] + kadv, smem + nbb + betaS[s]);
        asm volatile("s_waitcnt vmcnt(6)" ::: "memory");
      } else {
        asm volatile("s_waitcnt vmcnt(0)" ::: "memory");
      }
      __builtin_amdgcn_s_barrier();
      __builtin_amdgcn_sched_barrier(0);
#pragma unroll
      for (int kk = 0; kk < 2; ++kk) {
        const int colb = kk * 64 + ksel;
        bf16x8 af[2], bfr[4];
#pragma unroll
        for (int mi = 0; mi < 2; ++mi) {
          int row = qm * 32 + mi * 16 + rsel;
          af[mi] = *(const bf16x8*)(smem + abase + row * 128 + (colb ^ ((row & 7) << 4)));
        }
#pragma unroll
        for (int ni = 0; ni < 4; ++ni) {
          int row = ni * 16 + rsel;
          bfr[ni] = *(const bf16x8*)(smem + bbase + row * 128 + (colb ^ ((row & 7) << 4)));
        }
#pragma unroll
        for (int mi = 0; mi < 2; ++mi)
#pragma unroll
          for (int ni = 0; ni < 4; ++ni)
            acc[mi][ni] = __builtin_amdgcn_mfma_f32_16x16x32_bf16(af[mi], bfr[ni], acc[mi][ni], 0, 0, 0);
      }
      __builtin_amdgcn_s_barrier();
      __builtin_amdgcn_sched_barrier(0);
    }

    // epilogue: gates = acc + GX(LDS); cell on register c; h via write-through stores
    const char* lsGX = smem + 49152;
    float* partW = partAll + (size_t)t * PARTSZ_;
#pragma unroll
    for (int mi = 0; mi < 2; ++mi) {
#pragma unroll
      for (int r = 0; r < 4; ++r) {
        int grow = qm * 32 + mi * 16 + rbase + r;  // row within 128-tile
        int b = m0 + grow;
        int gxswz = (grow & 7) << 4;
        float gx0 = __uint_as_float(
            (u32)*(const u16*)(lsGX + ((grow << 7) | ((cbase << 1) ^ gxswz))) << 16);
        float gx1 = __uint_as_float(
            (u32)*(const u16*)(lsGX + ((grow << 7) | ((((16 + cbase) << 1)) ^ gxswz))) << 16);
        float gx2 = __uint_as_float(
            (u32)*(const u16*)(lsGX + ((grow << 7) | ((((32 + cbase) << 1)) ^ gxswz))) << 16);
        float gx3 = __uint_as_float(
            (u32)*(const u16*)(lsGX + ((grow << 7) | ((((48 + cbase) << 1)) ^ gxswz))) << 16);
        float gi = acc[mi][0][r] + gx0;
        float gf = acc[mi][1][r] + gx1;
        float gg = acc[mi][2][r] + gx2;
        float go = acc[mi][3][r] + gx3;
        float c2 = fsig(gf) * creg[mi][r] + fsig(gi) * ftanh(gg);
        float h2 = fsig(go) * ftanh(c2);
        creg[mi][r] = c2;
        store_wt16(hbW + (size_t)b * H_ + j, f2bf(h2));
        float p0 = c2 * w0, p1 = c2 * w1;
#pragma unroll
        for (int off = 1; off < 16; off <<= 1) {
          p0 += __shfl_xor(p0, off);
          p1 += __shfl_xor(p1, off);
        }
        if (cbase == 0) {
          partW[(b << 7) + bx] = p0;
          partW[(b << 7) + 64 + bx] = p1;
        }
      }
    }

    // signal: own stores (write-through) at coherence point once vmcnt drains
    asm volatile("s_waitcnt vmcnt(0)" ::: "memory");
    __syncthreads();
    if (tid == 0)
      __hip_atomic_store(flags + (size_t)t * NBLK_ + by * 64 + bx, 1u,
                         __ATOMIC_RELAXED, __HIP_MEMORY_SCOPE_AGENT);
  }
}

// ---------- final: reduce ALL steps' partials -> out[t] log-softmax; t=63 also raw out_final
__global__ void final_kernel(const float* __restrict__ partAll, const float* __restrict__ bout,
                             float* __restrict__ out) {
  int gid = blockIdx.x * 256 + threadIdx.x;  // 131072 = 64 t x 1024 b x 2 cls
  int t = gid >> 11;
  int r = gid & 2047;
  int b = r >> 1, cls = r & 1;
  const float4* pp = (const float4*)(partAll + (size_t)t * PARTSZ_ + (b << 7) + cls * 64);
  float4 sv = {0.f, 0.f, 0.f, 0.f};
#pragma unroll
  for (int q = 0; q < 16; ++q) {
    float4 v = pp[q];
    sv.x += v.x; sv.y += v.y; sv.z += v.z; sv.w += v.w;
  }
  float l = sv.x + sv.y + sv.z + sv.w + bout[cls];
  float other = __shfl_xor(l, 1);
  float m = fmaxf(l, other);
  float ls = m + __logf(__expf(l - m) + __expf(other - m));
  out[(size_t)t * (B_ * 2) + b * 2 + cls] = l - ls;
  if (t == 63) out[(size_t)T_ * (B_ * 2) + b * 2 + cls] = l;  // out_final raw
}

extern "C" void kernel_launch(void* const* d_in, const int* in_sizes, int n_in,
                              void* d_out, int out_size, void* d_ws, size_t ws_size,
                              hipStream_t stream) {
  const int* x      = (const int*)d_in[0];
  const float* emb  = (const float*)d_in[1];
  const float* W_ih = (const float*)d_in[2];
  const float* W_hh = (const float*)d_in[3];
  const float* b_ih = (const float*)d_in[4];
  const float* b_hh = (const float*)d_in[5];
  const float* W_out = (const float*)d_in[6];
  const float* b_out = (const float*)d_in[7];
  const float* h0   = (const float*)d_in[8];
  const float* c0   = (const float*)d_in[9];
  float* out = (float*)d_out;

  // workspace (~691 MB): XEall region is DEAD after xproj -> reused as the h ring.
  char* w = (char*)d_ws;
  u16* WihP = (u16*)w;   w += (size_t)G4_ * H_ * 2;             // 8 MB
  u16* WhhP = (u16*)w;   w += (size_t)G4_ * H_ * 2;             // 8 MB
  u16* XEall = (u16*)w;  w += (size_t)T_ * HB_ * 2;             // 128 MB (= hring[1..64])
  u16* GXall = (u16*)w;  w += (size_t)T_ * B_ * G4_ * 2;        // 512 MB
  u16* h0slot = (u16*)w; w += (size_t)HB_ * 2;                  // 2 MB (hring[0])
  float* bcP = (float*)w;     w += (size_t)G4_ * 4;
  float* partAll = (float*)w; w += (size_t)T_ * PARTSZ_ * 4;    // 32 MB
  u32* flags = (u32*)w;       w += (size_t)T_ * NBLK_ * 4;      // 128 KB

  prep_kernel<<<5153, 256, 0, stream>>>(W_ih, W_hh, b_ih, b_hh, h0,
                                        WihP, WhhP, bcP, h0slot, flags);
  gather_kernel<<<dim3(B_, T_), 256, 0, stream>>>(x, emb, XEall);
  for (int ch = 0; ch < T_ / CHUNK_; ++ch) {
    xproj_kernel<<<4096, 256, 0, stream>>>(XEall + (size_t)ch * CHUNK_ * HB_, WihP, bcP,
                                           GXall + (size_t)ch * CHUNK_ * B_ * G4_);
  }
  rec_kernel<<<NBLK_, 256, 0, stream>>>(h0slot, XEall /*hring[1..]*/, WhhP, GXall, c0,
                                        partAll, W_out, flags);
  final_kernel<<<512, 256, 0, stream>>>(partAll, b_out, out);
}

// Round 11
// 1615.378 us; speedup vs baseline: 5.2952x; 1.0080x over previous
//
#include <hip/hip_runtime.h>

typedef __bf16 bf16x8 __attribute__((ext_vector_type(8)));
typedef float f32x4 __attribute__((ext_vector_type(4)));
typedef unsigned short u16;
typedef unsigned int u32;

#define T_ 64
#define B_ 1024
#define H_ 1024
#define G4_ 4096
#define HB_ (B_ * H_)
#define CHUNK_ 16
#define NBLK_ 512
#define PARTSZ_ (B_ * 2 * 64)

__device__ inline u16 f2bf(float f) {
  u32 u = __float_as_uint(f);
  u32 r = (u + 0x7fffu + ((u >> 16) & 1u)) >> 16;  // RNE
  return (u16)r;
}

__device__ inline uint2 cvt4(float4 v) {
  uint2 r;
  r.x = (u32)f2bf(v.x) | ((u32)f2bf(v.y) << 16);
  r.y = (u32)f2bf(v.z) | ((u32)f2bf(v.w) << 16);
  return r;
}

__device__ __forceinline__ void gload16(const void* g, void* l) {
  __builtin_amdgcn_global_load_lds(
      (const __attribute__((address_space(1))) unsigned int*)g,
      (__attribute__((address_space(3))) unsigned int*)l, 16, 0, 0);
}

// write-through 2B store: data lands at the coherence point (L3), never dirty in L2.
__device__ __forceinline__ void store_wt16(u16* p, u16 v) {
  asm volatile("global_store_short %0, %1, off sc0 sc1" :: "v"(p), "v"((u32)v) : "memory");
}

__device__ inline float fsig(float x) { return 1.f / (1.f + __expf(-x)); }
__device__ inline float ftanh(float x) {
  float e = __expf(2.f * x);
  return 1.f - 2.f / (e + 1.f);
}

// ---------- prep: WihP/WhhP gate-interleaved-row bf16 [4096][1024], bcP permuted bias,
// h0slot=bf16(h0), flags[64][512]=0.  Permutation: n' = (j>>4)*64 + gate*16 + (j&15)
__global__ void prep_kernel(const float* __restrict__ W_ih, const float* __restrict__ W_hh,
                            const float* __restrict__ b_ih, const float* __restrict__ b_hh,
                            const float* __restrict__ h0,
                            u16* __restrict__ WihP, u16* __restrict__ WhhP,
                            float* __restrict__ bcP, u16* __restrict__ h0slot,
                            u32* __restrict__ flags) {
  int bid = blockIdx.x, tid = threadIdx.x;
  if (bid < 4096) {
    int np = bid;
    int gate = (np >> 4) & 3;
    int j = ((np >> 6) << 4) | (np & 15);
    size_t srow = (size_t)(gate * 1024 + j) * 1024;
    int base = tid << 2;
    *(uint2*)(WihP + (size_t)np * 1024 + base) = cvt4(*(const float4*)(W_ih + srow + base));
    *(uint2*)(WhhP + (size_t)np * 1024 + base) = cvt4(*(const float4*)(W_hh + srow + base));
  } else if (bid < 5120) {
    int i = ((bid - 4096) * 256 + tid) << 2;
    *(uint2*)(h0slot + i) = cvt4(*(const float4*)(h0 + i));
  } else if (bid == 5120) {
#pragma unroll
    for (int q = 0; q < 16; ++q) {
      int np = q * 256 + tid;
      int gate = (np >> 4) & 3;
      int j = ((np >> 6) << 4) | (np & 15);
      int srcn = gate * 1024 + j;
      bcP[np] = b_ih[srcn] + b_hh[srcn];
    }
  } else {
    int idx = ((bid - 5121) * 256 + tid) << 2;  // 32 blocks x 1024 u32 = 32768
    *(uint4*)(flags + idx) = uint4{0u, 0u, 0u, 0u};
  }
}

// ---------- gather ALL 64 steps: XEall[t][b][:] = bf16(emb[x[b,t]])
__global__ void gather_kernel(const int* __restrict__ x, const float* __restrict__ emb,
                              u16* __restrict__ XEall) {
  int b = blockIdx.x, tc = blockIdx.y;
  int row = x[b * T_ + tc];
  int e = threadIdx.x << 2;
  float4 v = *(const float4*)(emb + (size_t)row * H_ + e);
  *(uint2*)(XEall + ((size_t)tc * B_ + b) * H_ + e) = cvt4(v);
}

// ---------- x-projection big GEMM (128x128, 4 waves of 64x64, BK=64, single LDS buf):
// GXc[gm][n'] = bf16( XEc[gm].WihP[n'] + bcP[n'] ),  M = 16*1024, N = 4096, K = 1024.
__global__ void __launch_bounds__(256, 2) xproj_kernel(
    const u16* __restrict__ XEc, const u16* __restrict__ WihP,
    const float* __restrict__ bcP, u16* __restrict__ GXc) {
  __shared__ char smem[32768];  // lsA [128][128B] + lsB [128][128B]
  const int tid = threadIdx.x;
  const int lane = tid & 63;
  const int wave = tid >> 6;
  const int wm = wave >> 1, wn = wave & 1;
  const int hbid = blockIdx.x;  // 4096 = 8 XCD x 512
  const int xcd = hbid & 7;
  const int s9 = hbid >> 3;           // [0,512)
  const int mg = s9 >> 7;             // 4 m-groups
  const int rem = s9 & 127;
  const int n0 = (rem >> 2) * 128;    // 32 n-tiles, inner sweep
  const int m0 = (xcd * 16 + mg * 4 + (rem & 3)) * 128;

  const u16* srcA[4];
  const u16* srcB[4];
  int betaA[4], betaB[4];
#pragma unroll
  for (int s = 0; s < 4; ++s) {
    int beta = (s * 256 + tid) * 16;             // 0..16K
    int row = beta >> 7;                         // 128B rows
    int colu = (beta & 127) ^ ((row & 7) << 4);  // pre-swizzled source col
    int kl = colu >> 1;
    srcA[s] = XEc + (size_t)(m0 + row) * 1024 + kl;
    srcB[s] = WihP + (size_t)(n0 + row) * 1024 + kl;
    betaA[s] = beta;
    betaB[s] = 16384 + beta;
  }

  f32x4 acc[4][4] = {};
  const int rsel = lane & 15;
  const int ksel = (lane >> 4) << 4;

  for (int kt = 0; kt < 16; ++kt) {
#pragma unroll
    for (int s = 0; s < 4; ++s) gload16(srcA[s], smem + betaA[s]);
#pragma unroll
    for (int s = 0; s < 4; ++s) gload16(srcB[s], smem + betaB[s]);
#pragma unroll
    for (int s = 0; s < 4; ++s) { srcA[s] += 64; srcB[s] += 64; }
    __syncthreads();
#pragma unroll
    for (int kk = 0; kk < 2; ++kk) {
      const int colb = kk * 64 + ksel;
      bf16x8 af[4], bfr[4];
#pragma unroll
      for (int mi = 0; mi < 4; ++mi) {
        int row = wm * 64 + mi * 16 + rsel;
        af[mi] = *(const bf16x8*)(smem + row * 128 + (colb ^ ((row & 7) << 4)));
      }
#pragma unroll
      for (int ni = 0; ni < 4; ++ni) {
        int row = wn * 64 + ni * 16 + rsel;
        bfr[ni] = *(const bf16x8*)(smem + 16384 + row * 128 + (colb ^ ((row & 7) << 4)));
      }
#pragma unroll
      for (int mi = 0; mi < 4; ++mi)
#pragma unroll
        for (int ni = 0; ni < 4; ++ni)
          acc[mi][ni] = __builtin_amdgcn_mfma_f32_16x16x32_bf16(af[mi], bfr[ni], acc[mi][ni], 0, 0, 0);
    }
    __syncthreads();
  }

  const int rbase = (lane >> 4) << 2;
  const int cbase = lane & 15;
  float bc[4];
#pragma unroll
  for (int ni = 0; ni < 4; ++ni) bc[ni] = bcP[n0 + wn * 64 + ni * 16 + cbase];
#pragma unroll
  for (int mi = 0; mi < 4; ++mi) {
#pragma unroll
    for (int ni = 0; ni < 4; ++ni) {
      int gc = n0 + wn * 64 + ni * 16 + cbase;
#pragma unroll
      for (int r = 0; r < 4; ++r) {
        int gm = m0 + wm * 64 + mi * 16 + rbase + r;
        GXc[(size_t)gm * G4_ + gc] = f2bf(acc[mi][ni][r] + bc[ni]);
      }
    }
  }
}

// ---------- persistent recurrent kernel: all 64 steps, NO fences.
// h via write-through stores + per-step fresh ring buffer. Per-group flag barrier.
// GX double-buffered in LDS; GX(t+1) issued at kt=14 of step t (newest in vmcnt
// queue -> stays in flight through vmcnt(10)/vmcnt(4), drained by the epilogue's
// h-store vmcnt(0)) -> zero exposed GX latency at step start. c in registers.
__global__ void __launch_bounds__(256, 2) rec_kernel(
    const u16* __restrict__ h0slot, u16* __restrict__ hring,
    const u16* __restrict__ WhhP, const u16* __restrict__ GXall,
    const float* __restrict__ c0, float* __restrict__ partAll,
    const float* __restrict__ Wout, u32* __restrict__ flags) {
  __shared__ char smem[81920];  // A dbuf 2x16K | B dbuf 2x8K @32768 | GX dbuf 2x16K @49152
  const int tid = threadIdx.x;
  const int lane = tid & 63;
  const int qm = tid >> 6;  // wave = m-slice [0,4)
  const int hbid = blockIdx.x;
  const int L = (hbid & 7) * 64 + (hbid >> 3);  // XCD swizzle: W n-slice per XCD
  const int bx = L >> 3;   // [0,64): n-tile
  const int by = L & 7;    // [0,8): m-tile
  const int n0 = bx * 64;
  const int m0 = by * 128;

  int offA[4], offGX[4], betaS[4];
  int offB[2];
#pragma unroll
  for (int s = 0; s < 4; ++s) {
    int beta = (s * 256 + tid) * 16;             // 0..16K
    int row = beta >> 7;
    int colu = (beta & 127) ^ ((row & 7) << 4);
    offA[s] = (m0 + row) * 1024 + (colu >> 1);
    offGX[s] = (m0 + row) * G4_ + n0 + (colu >> 1);
    betaS[s] = beta;
  }
#pragma unroll
  for (int s = 0; s < 2; ++s) {
    int beta = (s * 256 + tid) * 16;             // 0..8K
    int row = beta >> 7;
    int colu = (beta & 127) ^ ((row & 7) << 4);
    offB[s] = (n0 + row) * 1024 + (colu >> 1);
  }

  const int rsel = lane & 15;
  const int ksel = (lane >> 4) << 4;
  const int rbase = (lane >> 4) << 2;
  const int cbase = lane & 15;
  const int j = bx * 16 + cbase;
  const float w0 = Wout[j], w1 = Wout[1024 + j];

  // cell state lives in registers for the whole sequence
  float creg[2][4];
#pragma unroll
  for (int mi = 0; mi < 2; ++mi)
#pragma unroll
    for (int r = 0; r < 4; ++r)
      creg[mi][r] = c0[(size_t)(m0 + qm * 32 + mi * 16 + rbase + r) * H_ + j];

  // GX(0) -> gx buffer 0 (drained by kt0's vmcnt(6); visible after first barrier)
#pragma unroll
  for (int s = 0; s < 4; ++s) gload16(GXall + offGX[s], smem + 49152 + betaS[s]);

#pragma unroll 1
  for (int t = 0; t < T_; ++t) {
    if (t) {
      // group barrier: wait for the 64 same-by blocks (they wrote our h rows, step t-1)
      if (tid < 64) {
        const u32* fg = flags + (size_t)(t - 1) * NBLK_ + by * 64;
        int guard = 0;
        while (true) {
          u32 v = __hip_atomic_load(fg + tid, __ATOMIC_RELAXED, __HIP_MEMORY_SCOPE_AGENT);
          if (__all(v != 0)) break;
          __builtin_amdgcn_s_sleep(2);
          if (++guard > (1 << 18)) break;  // bounded: fail loud, never hang
        }
      }
      __syncthreads();  // no acquire fence: h buffer fresh; also closes gx-buffer reuse
    }

    // h ring: step t reads hring[t-1] (t=0 -> h0slot), writes hring[t]
    const u16* hbR = t ? (hring + (size_t)(t - 1) * HB_) : h0slot;
    u16* hbW = hring + (size_t)t * HB_;

    // prologue: tile 0 -> buf0
#pragma unroll
    for (int s = 0; s < 4; ++s) gload16(hbR + offA[s], smem + betaS[s]);
#pragma unroll
    for (int s = 0; s < 2; ++s) gload16(WhhP + offB[s], smem + 32768 + betaS[s]);

    f32x4 acc[2][4] = {};
#pragma unroll
    for (int kt = 0; kt < 16; ++kt) {
      const int cur = kt & 1;
      const int abase = cur * 16384;
      const int bbase = 32768 + cur * 8192;
      if (kt < 15) {
        const int nab = (cur ^ 1) * 16384;
        const int nbb = 32768 + (cur ^ 1) * 8192;
        const int kadv = (kt + 1) * 64;
#pragma unroll
        for (int s = 0; s < 4; ++s) gload16(hbR + offA[s] + kadv, smem + nab + betaS[s]);
#pragma unroll
        for (int s = 0; s < 2; ++s) gload16(WhhP + offB[s] + kadv, smem + nbb + betaS[s]);
        if (kt == 14 && t + 1 < T_) {
          // GX(t+1) prefetch: newest in queue -> survives vmcnt(10)/vmcnt(4),
          // drained by epilogue's vmcnt(0) (h-store drain) -> latency fully hidden.
          const u16* GXn = GXall + (size_t)(t + 1) * B_ * G4_;
          const int gxb = 49152 + ((t + 1) & 1) * 16384;
#pragma unroll
          for (int s = 0; s < 4; ++s) gload16(GXn + offGX[s], smem + gxb + betaS[s]);
          asm volatile("s_waitcnt vmcnt(10)" ::: "memory");
        } else {
          asm volatile("s_waitcnt vmcnt(6)" ::: "memory");
        }
      } else {
        if (t + 1 < T_) {
          asm volatile("s_waitcnt vmcnt(4)" ::: "memory");  // keep GX(t+1) in flight
        } else {
          asm volatile("s_waitcnt vmcnt(0)" ::: "memory");
        }
      }
      __builtin_amdgcn_s_barrier();
      __builtin_amdgcn_sched_barrier(0);
#pragma unroll
      for (int kk = 0; kk < 2; ++kk) {
        const int colb = kk * 64 + ksel;
        bf16x8 af[2], bfr[4];
#pragma unroll
        for (int mi = 0; mi < 2; ++mi) {
          int row = qm * 32 + mi * 16 + rsel;
          af[mi] = *(const bf16x8*)(smem + abase + row * 128 + (colb ^ ((row & 7) << 4)));
        }
#pragma unroll
        for (int ni = 0; ni < 4; ++ni) {
          int row = ni * 16 + rsel;
          bfr[ni] = *(const bf16x8*)(smem + bbase + row * 128 + (colb ^ ((row & 7) << 4)));
        }
#pragma unroll
        for (int mi = 0; mi < 2; ++mi)
#pragma unroll
          for (int ni = 0; ni < 4; ++ni)
            acc[mi][ni] = __builtin_amdgcn_mfma_f32_16x16x32_bf16(af[mi], bfr[ni], acc[mi][ni], 0, 0, 0);
      }
      __builtin_amdgcn_s_barrier();
      __builtin_amdgcn_sched_barrier(0);
    }

    // epilogue pass 1: gates = acc + GX(LDS); cell on register c; write-through h
    const char* lsGX = smem + 49152 + (t & 1) * 16384;
#pragma unroll
    for (int mi = 0; mi < 2; ++mi) {
#pragma unroll
      for (int r = 0; r < 4; ++r) {
        int grow = qm * 32 + mi * 16 + rbase + r;  // row within 128-tile
        int b = m0 + grow;
        int gxswz = (grow & 7) << 4;
        float gx0 = __uint_as_float(
            (u32)*(const u16*)(lsGX + ((grow << 7) | ((cbase << 1) ^ gxswz))) << 16);
        float gx1 = __uint_as_float(
            (u32)*(const u16*)(lsGX + ((grow << 7) | ((((16 + cbase) << 1)) ^ gxswz))) << 16);
        float gx2 = __uint_as_float(
            (u32)*(const u16*)(lsGX + ((grow << 7) | ((((32 + cbase) << 1)) ^ gxswz))) << 16);
        float gx3 = __uint_as_float(
            (u32)*(const u16*)(lsGX + ((grow << 7) | ((((48 + cbase) << 1)) ^ gxswz))) << 16);
        float gi = acc[mi][0][r] + gx0;
        float gf = acc[mi][1][r] + gx1;
        float gg = acc[mi][2][r] + gx2;
        float go = acc[mi][3][r] + gx3;
        float c2 = fsig(gf) * creg[mi][r] + fsig(gi) * ftanh(gg);
        float h2 = fsig(go) * ftanh(c2);
        creg[mi][r] = c2;
        store_wt16(hbW + (size_t)b * H_ + j, f2bf(h2));
      }
    }

    // signal ASAP: h stores at coherence point once vmcnt drains (also lands GX(t+1))
    asm volatile("s_waitcnt vmcnt(0)" ::: "memory");
    __syncthreads();
    if (tid == 0)
      __hip_atomic_store(flags + (size_t)t * NBLK_ + by * 64 + bx, 1u,
                         __ATOMIC_RELAXED, __HIP_MEMORY_SCOPE_AGENT);

    // epilogue pass 2 (off critical path): head partials from creg
    float* partW = partAll + (size_t)t * PARTSZ_;
#pragma unroll
    for (int mi = 0; mi < 2; ++mi) {
#pragma unroll
      for (int r = 0; r < 4; ++r) {
        int b = m0 + qm * 32 + mi * 16 + rbase + r;
        float p0 = creg[mi][r] * w0, p1 = creg[mi][r] * w1;
#pragma unroll
        for (int off = 1; off < 16; off <<= 1) {
          p0 += __shfl_xor(p0, off);
          p1 += __shfl_xor(p1, off);
        }
        if (cbase == 0) {
          partW[(b << 7) + bx] = p0;
          partW[(b << 7) + 64 + bx] = p1;
        }
      }
    }
  }
}

// ---------- final: reduce ALL steps' partials -> out[t] log-softmax; t=63 also raw out_final
__global__ void final_kernel(const float* __restrict__ partAll, const float* __restrict__ bout,
                             float* __restrict__ out) {
  int gid = blockIdx.x * 256 + threadIdx.x;  // 131072 = 64 t x 1024 b x 2 cls
  int t = gid >> 11;
  int r = gid & 2047;
  int b = r >> 1, cls = r & 1;
  const float4* pp = (const float4*)(partAll + (size_t)t * PARTSZ_ + (b << 7) + cls * 64);
  float4 sv = {0.f, 0.f, 0.f, 0.f};
#pragma unroll
  for (int q = 0; q < 16; ++q) {
    float4 v = pp[q];
    sv.x += v.x; sv.y += v.y; sv.z += v.z; sv.w += v.w;
  }
  float l = sv.x + sv.y + sv.z + sv.w + bout[cls];
  float other = __shfl_xor(l, 1);
  float m = fmaxf(l, other);
  float ls = m + __logf(__expf(l - m) + __expf(other - m));
  out[(size_t)t * (B_ * 2) + b * 2 + cls] = l - ls;
  if (t == 63) out[(size_t)T_ * (B_ * 2) + b * 2 + cls] = l;  // out_final raw
}

extern "C" void kernel_launch(void* const* d_in, const int* in_sizes, int n_in,
                              void* d_out, int out_size, void* d_ws, size_t ws_size,
                              hipStream_t stream) {
  const int* x      = (const int*)d_in[0];
  const float* emb  = (const float*)d_in[1];
  const float* W_ih = (const float*)d_in[2];
  const float* W_hh = (const float*)d_in[3];
  const float* b_ih = (const float*)d_in[4];
  const float* b_hh = (const float*)d_in[5];
  const float* W_out = (const float*)d_in[6];
  const float* b_out = (const float*)d_in[7];
  const float* h0   = (const float*)d_in[8];
  const float* c0   = (const float*)d_in[9];
  float* out = (float*)d_out;

  // workspace (~691 MB): XEall region is DEAD after xproj -> reused as the h ring.
  char* w = (char*)d_ws;
  u16* WihP = (u16*)w;   w += (size_t)G4_ * H_ * 2;             // 8 MB
  u16* WhhP = (u16*)w;   w += (size_t)G4_ * H_ * 2;             // 8 MB
  u16* XEall = (u16*)w;  w += (size_t)T_ * HB_ * 2;             // 128 MB (= hring[1..64])
  u16* GXall = (u16*)w;  w += (size_t)T_ * B_ * G4_ * 2;        // 512 MB
  u16* h0slot = (u16*)w; w += (size_t)HB_ * 2;                  // 2 MB (hring[0])
  float* bcP = (float*)w;     w += (size_t)G4_ * 4;
  float* partAll = (float*)w; w += (size_t)T_ * PARTSZ_ * 4;    // 32 MB
  u32* flags = (u32*)w;       w += (size_t)T_ * NBLK_ * 4;      // 128 KB

  prep_kernel<<<5153, 256, 0, stream>>>(W_ih, W_hh, b_ih, b_hh, h0,
                                        WihP, WhhP, bcP, h0slot, flags);
  gather_kernel<<<dim3(B_, T_), 256, 0, stream>>>(x, emb, XEall);
  for (int ch = 0; ch < T_ / CHUNK_; ++ch) {
    xproj_kernel<<<4096, 256, 0, stream>>>(XEall + (size_t)ch * CHUNK_ * HB_, WihP, bcP,
                                           GXall + (size_t)ch * CHUNK_ * B_ * G4_);
  }
  rec_kernel<<<NBLK_, 256, 0, stream>>>(h0slot, XEall /*hring[1..]*/, WhhP, GXall, c0,
                                        partAll, W_out, flags);
  final_kernel<<<512, 256, 0, stream>>>(partAll, b_out, out);
}

// Round 12
// 1596.506 us; speedup vs baseline: 5.3578x; 1.0118x over previous
//
#include <hip/hip_runtime.h>

typedef __bf16 bf16x8 __attribute__((ext_vector_type(8)));
typedef float f32x4 __attribute__((ext_vector_type(4)));
typedef unsigned short u16;
typedef unsigned int u32;

#define T_ 64
#define B_ 1024
#define H_ 1024
#define G4_ 4096
#define HB_ (B_ * H_)
#define CHUNK_ 16
#define NBLK_ 512
#define PARTSZ_ (B_ * 2 * 64)

__device__ inline u16 f2bf(float f) {
  u32 u = __float_as_uint(f);
  u32 r = (u + 0x7fffu + ((u >> 16) & 1u)) >> 16;  // RNE
  return (u16)r;
}

__device__ inline uint2 cvt4(float4 v) {
  uint2 r;
  r.x = (u32)f2bf(v.x) | ((u32)f2bf(v.y) << 16);
  r.y = (u32)f2bf(v.z) | ((u32)f2bf(v.w) << 16);
  return r;
}

__device__ __forceinline__ void gload16(const void* g, void* l) {
  __builtin_amdgcn_global_load_lds(
      (const __attribute__((address_space(1))) unsigned int*)g,
      (__attribute__((address_space(3))) unsigned int*)l, 16, 0, 0);
}

// non-temporal variant (CPol NT on gfx94x+): stream, don't allocate in L2/L3.
__device__ __forceinline__ void gload16_nt(const void* g, void* l) {
  __builtin_amdgcn_global_load_lds(
      (const __attribute__((address_space(1))) unsigned int*)g,
      (__attribute__((address_space(3))) unsigned int*)l, 16, 0, 2);
}

// write-through 2B store: data lands at the coherence point (L3), never dirty in L2.
__device__ __forceinline__ void store_wt16(u16* p, u16 v) {
  asm volatile("global_store_short %0, %1, off sc0 sc1" :: "v"(p), "v"((u32)v) : "memory");
}

__device__ inline float fsig(float x) { return 1.f / (1.f + __expf(-x)); }
__device__ inline float ftanh(float x) {
  float e = __expf(2.f * x);
  return 1.f - 2.f / (e + 1.f);
}

// ---------- prep: WihP/WhhP gate-interleaved-row bf16 [4096][1024], bcP permuted bias,
// h0slot=bf16(h0), flags[64][512]=0.  Permutation: n' = (j>>4)*64 + gate*16 + (j&15)
__global__ void prep_kernel(const float* __restrict__ W_ih, const float* __restrict__ W_hh,
                            const float* __restrict__ b_ih, const float* __restrict__ b_hh,
                            const float* __restrict__ h0,
                            u16* __restrict__ WihP, u16* __restrict__ WhhP,
                            float* __restrict__ bcP, u16* __restrict__ h0slot,
                            u32* __restrict__ flags) {
  int bid = blockIdx.x, tid = threadIdx.x;
  if (bid < 4096) {
    int np = bid;
    int gate = (np >> 4) & 3;
    int j = ((np >> 6) << 4) | (np & 15);
    size_t srow = (size_t)(gate * 1024 + j) * 1024;
    int base = tid << 2;
    *(uint2*)(WihP + (size_t)np * 1024 + base) = cvt4(*(const float4*)(W_ih + srow + base));
    *(uint2*)(WhhP + (size_t)np * 1024 + base) = cvt4(*(const float4*)(W_hh + srow + base));
  } else if (bid < 5120) {
    int i = ((bid - 4096) * 256 + tid) << 2;
    *(uint2*)(h0slot + i) = cvt4(*(const float4*)(h0 + i));
  } else if (bid == 5120) {
#pragma unroll
    for (int q = 0; q < 16; ++q) {
      int np = q * 256 + tid;
      int gate = (np >> 4) & 3;
      int j = ((np >> 6) << 4) | (np & 15);
      int srcn = gate * 1024 + j;
      bcP[np] = b_ih[srcn] + b_hh[srcn];
    }
  } else {
    int idx = ((bid - 5121) * 256 + tid) << 2;  // 32 blocks x 1024 u32 = 32768
    *(uint4*)(flags + idx) = uint4{0u, 0u, 0u, 0u};
  }
}

// ---------- gather ALL 64 steps: XEall[t][b][:] = bf16(emb[x[b,t]])
__global__ void gather_kernel(const int* __restrict__ x, const float* __restrict__ emb,
                              u16* __restrict__ XEall) {
  int b = blockIdx.x, tc = blockIdx.y;
  int row = x[b * T_ + tc];
  int e = threadIdx.x << 2;
  float4 v = *(const float4*)(emb + (size_t)row * H_ + e);
  *(uint2*)(XEall + ((size_t)tc * B_ + b) * H_ + e) = cvt4(v);
}

// ---------- x-projection big GEMM (128x128, 4 waves of 64x64, BK=64, single LDS buf):
// GXc[gm][n'] = bf16( XEc[gm].WihP[n'] + bcP[n'] ),  M = 16*1024, N = 4096, K = 1024.
__global__ void __launch_bounds__(256, 2) xproj_kernel(
    const u16* __restrict__ XEc, const u16* __restrict__ WihP,
    const float* __restrict__ bcP, u16* __restrict__ GXc) {
  __shared__ char smem[32768];  // lsA [128][128B] + lsB [128][128B]
  const int tid = threadIdx.x;
  const int lane = tid & 63;
  const int wave = tid >> 6;
  const int wm = wave >> 1, wn = wave & 1;
  const int hbid = blockIdx.x;  // 4096 = 8 XCD x 512
  const int xcd = hbid & 7;
  const int s9 = hbid >> 3;           // [0,512)
  const int mg = s9 >> 7;             // 4 m-groups
  const int rem = s9 & 127;
  const int n0 = (rem >> 2) * 128;    // 32 n-tiles, inner sweep
  const int m0 = (xcd * 16 + mg * 4 + (rem & 3)) * 128;

  const u16* srcA[4];
  const u16* srcB[4];
  int betaA[4], betaB[4];
#pragma unroll
  for (int s = 0; s < 4; ++s) {
    int beta = (s * 256 + tid) * 16;             // 0..16K
    int row = beta >> 7;                         // 128B rows
    int colu = (beta & 127) ^ ((row & 7) << 4);  // pre-swizzled source col
    int kl = colu >> 1;
    srcA[s] = XEc + (size_t)(m0 + row) * 1024 + kl;
    srcB[s] = WihP + (size_t)(n0 + row) * 1024 + kl;
    betaA[s] = beta;
    betaB[s] = 16384 + beta;
  }

  f32x4 acc[4][4] = {};
  const int rsel = lane & 15;
  const int ksel = (lane >> 4) << 4;

  for (int kt = 0; kt < 16; ++kt) {
#pragma unroll
    for (int s = 0; s < 4; ++s) gload16(srcA[s], smem + betaA[s]);
#pragma unroll
    for (int s = 0; s < 4; ++s) gload16(srcB[s], smem + betaB[s]);
#pragma unroll
    for (int s = 0; s < 4; ++s) { srcA[s] += 64; srcB[s] += 64; }
    __syncthreads();
#pragma unroll
    for (int kk = 0; kk < 2; ++kk) {
      const int colb = kk * 64 + ksel;
      bf16x8 af[4], bfr[4];
#pragma unroll
      for (int mi = 0; mi < 4; ++mi) {
        int row = wm * 64 + mi * 16 + rsel;
        af[mi] = *(const bf16x8*)(smem + row * 128 + (colb ^ ((row & 7) << 4)));
      }
#pragma unroll
      for (int ni = 0; ni < 4; ++ni) {
        int row = wn * 64 + ni * 16 + rsel;
        bfr[ni] = *(const bf16x8*)(smem + 16384 + row * 128 + (colb ^ ((row & 7) << 4)));
      }
#pragma unroll
      for (int mi = 0; mi < 4; ++mi)
#pragma unroll
        for (int ni = 0; ni < 4; ++ni)
          acc[mi][ni] = __builtin_amdgcn_mfma_f32_16x16x32_bf16(af[mi], bfr[ni], acc[mi][ni], 0, 0, 0);
    }
    __syncthreads();
  }

  const int rbase = (lane >> 4) << 2;
  const int cbase = lane & 15;
  float bc[4];
#pragma unroll
  for (int ni = 0; ni < 4; ++ni) bc[ni] = bcP[n0 + wn * 64 + ni * 16 + cbase];
#pragma unroll
  for (int mi = 0; mi < 4; ++mi) {
#pragma unroll
    for (int ni = 0; ni < 4; ++ni) {
      int gc = n0 + wn * 64 + ni * 16 + cbase;
#pragma unroll
      for (int r = 0; r < 4; ++r) {
        int gm = m0 + wm * 64 + mi * 16 + rbase + r;
        GXc[(size_t)gm * G4_ + gc] = f2bf(acc[mi][ni][r] + bc[ni]);
      }
    }
  }
}

// ---------- persistent recurrent kernel: all 64 steps, NO fences.
// h via write-through stores + per-step fresh ring buffer. Per-group flag barrier.
// GX loads are NON-TEMPORAL (don't pollute L2/L3 -> Whh + h-ring stay cache-resident).
// GX(t+1) issued in the epilogue AFTER the h stores: vmcnt(4) drains stores only,
// flag fires immediately; kt0's vmcnt(6) next step absorbs GX. c in registers.
__global__ void __launch_bounds__(256, 2) rec_kernel(
    const u16* __restrict__ h0slot, u16* __restrict__ hring,
    const u16* __restrict__ WhhP, const u16* __restrict__ GXall,
    const float* __restrict__ c0, float* __restrict__ partAll,
    const float* __restrict__ Wout, u32* __restrict__ flags) {
  __shared__ char smem[81920];  // A dbuf 2x16K | B dbuf 2x8K @32768 | GX dbuf 2x16K @49152
  const int tid = threadIdx.x;
  const int lane = tid & 63;
  const int qm = tid >> 6;  // wave = m-slice [0,4)
  const int hbid = blockIdx.x;
  const int L = (hbid & 7) * 64 + (hbid >> 3);  // XCD swizzle: W n-slice per XCD
  const int bx = L >> 3;   // [0,64): n-tile
  const int by = L & 7;    // [0,8): m-tile
  const int n0 = bx * 64;
  const int m0 = by * 128;

  int offA[4], offGX[4], betaS[4];
  int offB[2];
#pragma unroll
  for (int s = 0; s < 4; ++s) {
    int beta = (s * 256 + tid) * 16;             // 0..16K
    int row = beta >> 7;
    int colu = (beta & 127) ^ ((row & 7) << 4);
    offA[s] = (m0 + row) * 1024 + (colu >> 1);
    offGX[s] = (m0 + row) * G4_ + n0 + (colu >> 1);
    betaS[s] = beta;
  }
#pragma unroll
  for (int s = 0; s < 2; ++s) {
    int beta = (s * 256 + tid) * 16;             // 0..8K
    int row = beta >> 7;
    int colu = (beta & 127) ^ ((row & 7) << 4);
    offB[s] = (n0 + row) * 1024 + (colu >> 1);
  }

  const int rsel = lane & 15;
  const int ksel = (lane >> 4) << 4;
  const int rbase = (lane >> 4) << 2;
  const int cbase = lane & 15;
  const int j = bx * 16 + cbase;
  const float w0 = Wout[j], w1 = Wout[1024 + j];

  // cell state lives in registers for the whole sequence
  float creg[2][4];
#pragma unroll
  for (int mi = 0; mi < 2; ++mi)
#pragma unroll
    for (int r = 0; r < 4; ++r)
      creg[mi][r] = c0[(size_t)(m0 + qm * 32 + mi * 16 + rbase + r) * H_ + j];

  // GX(0) -> gx buffer 0 (NT; absorbed by kt0's vmcnt(6) of step 0)
#pragma unroll
  for (int s = 0; s < 4; ++s) gload16_nt(GXall + offGX[s], smem + 49152 + betaS[s]);

#pragma unroll 1
  for (int t = 0; t < T_; ++t) {
    // B(Whh) tile 0 -> buffer 0: barrier-independent, issue before the poll.
#pragma unroll
    for (int s = 0; s < 2; ++s) gload16(WhhP + offB[s], smem + 32768 + betaS[s]);

    if (t) {
      // group barrier: wait for the 64 same-by blocks (they wrote our h rows, step t-1)
      if (tid < 64) {
        const u32* fg = flags + (size_t)(t - 1) * NBLK_ + by * 64;
        int guard = 0;
        while (true) {
          u32 v = __hip_atomic_load(fg + tid, __ATOMIC_RELAXED, __HIP_MEMORY_SCOPE_AGENT);
          if (__all(v != 0)) break;
          __builtin_amdgcn_s_sleep(4);
          if (++guard > (1 << 18)) break;  // bounded: fail loud, never hang
        }
      }
      __syncthreads();  // no acquire fence: h buffer fresh, L2 never cached it
    }

    // h ring: step t reads hring[t-1] (t=0 -> h0slot), writes hring[t]
    const u16* hbR = t ? (hring + (size_t)(t - 1) * HB_) : h0slot;
    u16* hbW = hring + (size_t)t * HB_;

    // A(h) tile 0 (needs the barrier)
#pragma unroll
    for (int s = 0; s < 4; ++s) gload16(hbR + offA[s], smem + betaS[s]);

    f32x4 acc[2][4] = {};
#pragma unroll
    for (int kt = 0; kt < 16; ++kt) {
      const int cur = kt & 1;
      const int abase = cur * 16384;
      const int bbase = 32768 + cur * 8192;
      if (kt < 15) {
        const int nab = (cur ^ 1) * 16384;
        const int nbb = 32768 + (cur ^ 1) * 8192;
        const int kadv = (kt + 1) * 64;
#pragma unroll
        for (int s = 0; s < 4; ++s) gload16(hbR + offA[s] + kadv, smem + nab + betaS[s]);
#pragma unroll
        for (int s = 0; s < 2; ++s) gload16(WhhP + offB[s] + kadv, smem + nbb + betaS[s]);
        // kt0: queue = [4 GX, 2 B0, 4 A0, 6 tile1] -> vmcnt(6) waits GX+tile0 exactly.
        asm volatile("s_waitcnt vmcnt(6)" ::: "memory");
      } else {
        asm volatile("s_waitcnt vmcnt(0)" ::: "memory");
      }
      __builtin_amdgcn_s_barrier();
      __builtin_amdgcn_sched_barrier(0);
#pragma unroll
      for (int kk = 0; kk < 2; ++kk) {
        const int colb = kk * 64 + ksel;
        bf16x8 af[2], bfr[4];
#pragma unroll
        for (int mi = 0; mi < 2; ++mi) {
          int row = qm * 32 + mi * 16 + rsel;
          af[mi] = *(const bf16x8*)(smem + abase + row * 128 + (colb ^ ((row & 7) << 4)));
        }
#pragma unroll
        for (int ni = 0; ni < 4; ++ni) {
          int row = ni * 16 + rsel;
          bfr[ni] = *(const bf16x8*)(smem + bbase + row * 128 + (colb ^ ((row & 7) << 4)));
        }
#pragma unroll
        for (int mi = 0; mi < 2; ++mi)
#pragma unroll
          for (int ni = 0; ni < 4; ++ni)
            acc[mi][ni] = __builtin_amdgcn_mfma_f32_16x16x32_bf16(af[mi], bfr[ni], acc[mi][ni], 0, 0, 0);
      }
      __builtin_amdgcn_s_barrier();
      __builtin_amdgcn_sched_barrier(0);
    }

    // epilogue pass 1: gates = acc + GX(LDS); cell on register c; write-through h
    const char* lsGX = smem + 49152 + (t & 1) * 16384;
#pragma unroll
    for (int mi = 0; mi < 2; ++mi) {
#pragma unroll
      for (int r = 0; r < 4; ++r) {
        int grow = qm * 32 + mi * 16 + rbase + r;  // row within 128-tile
        int b = m0 + grow;
        int gxswz = (grow & 7) << 4;
        float gx0 = __uint_as_float(
            (u32)*(const u16*)(lsGX + ((grow << 7) | ((cbase << 1) ^ gxswz))) << 16);
        float gx1 = __uint_as_float(
            (u32)*(const u16*)(lsGX + ((grow << 7) | ((((16 + cbase) << 1)) ^ gxswz))) << 16);
        float gx2 = __uint_as_float(
            (u32)*(const u16*)(lsGX + ((grow << 7) | ((((32 + cbase) << 1)) ^ gxswz))) << 16);
        float gx3 = __uint_as_float(
            (u32)*(const u16*)(lsGX + ((grow << 7) | ((((48 + cbase) << 1)) ^ gxswz))) << 16);
        float gi = acc[mi][0][r] + gx0;
        float gf = acc[mi][1][r] + gx1;
        float gg = acc[mi][2][r] + gx2;
        float go = acc[mi][3][r] + gx3;
        float c2 = fsig(gf) * creg[mi][r] + fsig(gi) * ftanh(gg);
        float h2 = fsig(go) * ftanh(c2);
        creg[mi][r] = c2;
        store_wt16(hbW + (size_t)b * H_ + j, f2bf(h2));
      }
    }

    // GX(t+1) prefetch AFTER the stores (NT): newest in queue -> vmcnt(4) below
    // drains exactly the 8 h stores and leaves GX in flight.
    if (t + 1 < T_) {
      const u16* GXn = GXall + (size_t)(t + 1) * B_ * G4_;
      const int gxb = 49152 + ((t + 1) & 1) * 16384;
#pragma unroll
      for (int s = 0; s < 4; ++s) gload16_nt(GXn + offGX[s], smem + gxb + betaS[s]);
      asm volatile("s_waitcnt vmcnt(4)" ::: "memory");
    } else {
      asm volatile("s_waitcnt vmcnt(0)" ::: "memory");
    }
    __syncthreads();
    if (tid == 0)
      __hip_atomic_store(flags + (size_t)t * NBLK_ + by * 64 + bx, 1u,
                         __ATOMIC_RELAXED, __HIP_MEMORY_SCOPE_AGENT);

    // epilogue pass 2 (off critical path): head partials from creg
    float* partW = partAll + (size_t)t * PARTSZ_;
#pragma unroll
    for (int mi = 0; mi < 2; ++mi) {
#pragma unroll
      for (int r = 0; r < 4; ++r) {
        int b = m0 + qm * 32 + mi * 16 + rbase + r;
        float p0 = creg[mi][r] * w0, p1 = creg[mi][r] * w1;
#pragma unroll
        for (int off = 1; off < 16; off <<= 1) {
          p0 += __shfl_xor(p0, off);
          p1 += __shfl_xor(p1, off);
        }
        if (cbase == 0) {
          partW[(b << 7) + bx] = p0;
          partW[(b << 7) + 64 + bx] = p1;
        }
      }
    }
  }
}

// ---------- final: reduce ALL steps' partials -> out[t] log-softmax; t=63 also raw out_final
__global__ void final_kernel(const float* __restrict__ partAll, const float* __restrict__ bout,
                             float* __restrict__ out) {
  int gid = blockIdx.x * 256 + threadIdx.x;  // 131072 = 64 t x 1024 b x 2 cls
  int t = gid >> 11;
  int r = gid & 2047;
  int b = r >> 1, cls = r & 1;
  const float4* pp = (const float4*)(partAll + (size_t)t * PARTSZ_ + (b << 7) + cls * 64);
  float4 sv = {0.f, 0.f, 0.f, 0.f};
#pragma unroll
  for (int q = 0; q < 16; ++q) {
    float4 v = pp[q];
    sv.x += v.x; sv.y += v.y; sv.z += v.z; sv.w += v.w;
  }
  float l = sv.x + sv.y + sv.z + sv.w + bout[cls];
  float other = __shfl_xor(l, 1);
  float m = fmaxf(l, other);
  float ls = m + __logf(__expf(l - m) + __expf(other - m));
  out[(size_t)t * (B_ * 2) + b * 2 + cls] = l - ls;
  if (t == 63) out[(size_t)T_ * (B_ * 2) + b * 2 + cls] = l;  // out_final raw
}

extern "C" void kernel_launch(void* const* d_in, const int* in_sizes, int n_in,
                              void* d_out, int out_size, void* d_ws, size_t ws_size,
                              hipStream_t stream) {
  const int* x      = (const int*)d_in[0];
  const float* emb  = (const float*)d_in[1];
  const float* W_ih = (const float*)d_in[2];
  const float* W_hh = (const float*)d_in[3];
  const float* b_ih = (const float*)d_in[4];
  const float* b_hh = (const float*)d_in[5];
  const float* W_out = (const float*)d_in[6];
  const float* b_out = (const float*)d_in[7];
  const float* h0   = (const float*)d_in[8];
  const float* c0   = (const float*)d_in[9];
  float* out = (float*)d_out;

  // workspace (~691 MB): XEall region is DEAD after xproj -> reused as the h ring.
  char* w = (char*)d_ws;
  u16* WihP = (u16*)w;   w += (size_t)G4_ * H_ * 2;             // 8 MB
  u16* WhhP = (u16*)w;   w += (size_t)G4_ * H_ * 2;             // 8 MB
  u16* XEall = (u16*)w;  w += (size_t)T_ * HB_ * 2;             // 128 MB (= hring[1..64])
  u16* GXall = (u16*)w;  w += (size_t)T_ * B_ * G4_ * 2;        // 512 MB
  u16* h0slot = (u16*)w; w += (size_t)HB_ * 2;                  // 2 MB (hring[0])
  float* bcP = (float*)w;     w += (size_t)G4_ * 4;
  float* partAll = (float*)w; w += (size_t)T_ * PARTSZ_ * 4;    // 32 MB
  u32* flags = (u32*)w;       w += (size_t)T_ * NBLK_ * 4;      // 128 KB

  prep_kernel<<<5153, 256, 0, stream>>>(W_ih, W_hh, b_ih, b_hh, h0,
                                        WihP, WhhP, bcP, h0slot, flags);
  gather_kernel<<<dim3(B_, T_), 256, 0, stream>>>(x, emb, XEall);
  for (int ch = 0; ch < T_ / CHUNK_; ++ch) {
    xproj_kernel<<<4096, 256, 0, stream>>>(XEall + (size_t)ch * CHUNK_ * HB_, WihP, bcP,
                                           GXall + (size_t)ch * CHUNK_ * B_ * G4_);
  }
  rec_kernel<<<NBLK_, 256, 0, stream>>>(h0slot, XEall /*hring[1..]*/, WhhP, GXall, c0,
                                        partAll, W_out, flags);
  final_kernel<<<512, 256, 0, stream>>>(partAll, b_out, out);
}

// Round 13
// 1592.661 us; speedup vs baseline: 5.3707x; 1.0024x over previous
//
#include <hip/hip_runtime.h>

typedef __bf16 bf16x8 __attribute__((ext_vector_type(8)));
typedef float f32x4 __attribute__((ext_vector_type(4)));
typedef unsigned short u16;
typedef unsigned int u32;

#define T_ 64
#define B_ 1024
#define H_ 1024
#define G4_ 4096
#define HB_ (B_ * H_)
#define CHUNK_ 16
#define NBLK_ 512
#define PARTSZ_ (B_ * 2 * 64)

__device__ inline u16 f2bf(float f) {
  u32 u = __float_as_uint(f);
  u32 r = (u + 0x7fffu + ((u >> 16) & 1u)) >> 16;  // RNE
  return (u16)r;
}

__device__ inline uint2 cvt4(float4 v) {
  uint2 r;
  r.x = (u32)f2bf(v.x) | ((u32)f2bf(v.y) << 16);
  r.y = (u32)f2bf(v.z) | ((u32)f2bf(v.w) << 16);
  return r;
}

__device__ __forceinline__ void gload16(const void* g, void* l) {
  __builtin_amdgcn_global_load_lds(
      (const __attribute__((address_space(1))) unsigned int*)g,
      (__attribute__((address_space(3))) unsigned int*)l, 16, 0, 0);
}

// non-temporal variant (CPol NT on gfx94x+): stream, don't allocate in L2/L3.
__device__ __forceinline__ void gload16_nt(const void* g, void* l) {
  __builtin_amdgcn_global_load_lds(
      (const __attribute__((address_space(1))) unsigned int*)g,
      (__attribute__((address_space(3))) unsigned int*)l, 16, 0, 2);
}

// write-through 2B store: data lands at the coherence point (L3), never dirty in L2.
__device__ __forceinline__ void store_wt16(u16* p, u16 v) {
  asm volatile("global_store_short %0, %1, off sc0 sc1" :: "v"(p), "v"((u32)v) : "memory");
}

__device__ inline float fsig(float x) { return 1.f / (1.f + __expf(-x)); }
__device__ inline float ftanh(float x) {
  float e = __expf(2.f * x);
  return 1.f - 2.f / (e + 1.f);
}

// ---------- prep: WihP/WhhP gate-interleaved-row bf16 [4096][1024], bcP permuted bias,
// h0slot=bf16(h0), flags[64][512]=0.  Permutation: n' = (j>>4)*64 + gate*16 + (j&15)
__global__ void prep_kernel(const float* __restrict__ W_ih, const float* __restrict__ W_hh,
                            const float* __restrict__ b_ih, const float* __restrict__ b_hh,
                            const float* __restrict__ h0,
                            u16* __restrict__ WihP, u16* __restrict__ WhhP,
                            float* __restrict__ bcP, u16* __restrict__ h0slot,
                            u32* __restrict__ flags) {
  int bid = blockIdx.x, tid = threadIdx.x;
  if (bid < 4096) {
    int np = bid;
    int gate = (np >> 4) & 3;
    int j = ((np >> 6) << 4) | (np & 15);
    size_t srow = (size_t)(gate * 1024 + j) * 1024;
    int base = tid << 2;
    *(uint2*)(WihP + (size_t)np * 1024 + base) = cvt4(*(const float4*)(W_ih + srow + base));
    *(uint2*)(WhhP + (size_t)np * 1024 + base) = cvt4(*(const float4*)(W_hh + srow + base));
  } else if (bid < 5120) {
    int i = ((bid - 4096) * 256 + tid) << 2;
    *(uint2*)(h0slot + i) = cvt4(*(const float4*)(h0 + i));
  } else if (bid == 5120) {
#pragma unroll
    for (int q = 0; q < 16; ++q) {
      int np = q * 256 + tid;
      int gate = (np >> 4) & 3;
      int j = ((np >> 6) << 4) | (np & 15);
      int srcn = gate * 1024 + j;
      bcP[np] = b_ih[srcn] + b_hh[srcn];
    }
  } else {
    int idx = ((bid - 5121) * 256 + tid) << 2;  // 32 blocks x 1024 u32 = 32768
    *(uint4*)(flags + idx) = uint4{0u, 0u, 0u, 0u};
  }
}

// ---------- gather ALL 64 steps: XEall[t][b][:] = bf16(emb[x[b,t]])
__global__ void gather_kernel(const int* __restrict__ x, const float* __restrict__ emb,
                              u16* __restrict__ XEall) {
  int b = blockIdx.x, tc = blockIdx.y;
  int row = x[b * T_ + tc];
  int e = threadIdx.x << 2;
  float4 v = *(const float4*)(emb + (size_t)row * H_ + e);
  *(uint2*)(XEall + ((size_t)tc * B_ + b) * H_ + e) = cvt4(v);
}

// ---------- x-projection big GEMM (128x128, 4 waves of 64x64, BK=64, single LDS buf):
// GXc[gm][n'] = bf16( XEc[gm].WihP[n'] + bcP[n'] ),  M = 16*1024, N = 4096, K = 1024.
__global__ void __launch_bounds__(256, 2) xproj_kernel(
    const u16* __restrict__ XEc, const u16* __restrict__ WihP,
    const float* __restrict__ bcP, u16* __restrict__ GXc) {
  __shared__ char smem[32768];  // lsA [128][128B] + lsB [128][128B]
  const int tid = threadIdx.x;
  const int lane = tid & 63;
  const int wave = tid >> 6;
  const int wm = wave >> 1, wn = wave & 1;
  const int hbid = blockIdx.x;  // 4096 = 8 XCD x 512
  const int xcd = hbid & 7;
  const int s9 = hbid >> 3;           // [0,512)
  const int mg = s9 >> 7;             // 4 m-groups
  const int rem = s9 & 127;
  const int n0 = (rem >> 2) * 128;    // 32 n-tiles, inner sweep
  const int m0 = (xcd * 16 + mg * 4 + (rem & 3)) * 128;

  const u16* srcA[4];
  const u16* srcB[4];
  int betaA[4], betaB[4];
#pragma unroll
  for (int s = 0; s < 4; ++s) {
    int beta = (s * 256 + tid) * 16;             // 0..16K
    int row = beta >> 7;                         // 128B rows
    int colu = (beta & 127) ^ ((row & 7) << 4);  // pre-swizzled source col
    int kl = colu >> 1;
    srcA[s] = XEc + (size_t)(m0 + row) * 1024 + kl;
    srcB[s] = WihP + (size_t)(n0 + row) * 1024 + kl;
    betaA[s] = beta;
    betaB[s] = 16384 + beta;
  }

  f32x4 acc[4][4] = {};
  const int rsel = lane & 15;
  const int ksel = (lane >> 4) << 4;

  for (int kt = 0; kt < 16; ++kt) {
#pragma unroll
    for (int s = 0; s < 4; ++s) gload16(srcA[s], smem + betaA[s]);
#pragma unroll
    for (int s = 0; s < 4; ++s) gload16(srcB[s], smem + betaB[s]);
#pragma unroll
    for (int s = 0; s < 4; ++s) { srcA[s] += 64; srcB[s] += 64; }
    __syncthreads();
#pragma unroll
    for (int kk = 0; kk < 2; ++kk) {
      const int colb = kk * 64 + ksel;
      bf16x8 af[4], bfr[4];
#pragma unroll
      for (int mi = 0; mi < 4; ++mi) {
        int row = wm * 64 + mi * 16 + rsel;
        af[mi] = *(const bf16x8*)(smem + row * 128 + (colb ^ ((row & 7) << 4)));
      }
#pragma unroll
      for (int ni = 0; ni < 4; ++ni) {
        int row = wn * 64 + ni * 16 + rsel;
        bfr[ni] = *(const bf16x8*)(smem + 16384 + row * 128 + (colb ^ ((row & 7) << 4)));
      }
#pragma unroll
      for (int mi = 0; mi < 4; ++mi)
#pragma unroll
        for (int ni = 0; ni < 4; ++ni)
          acc[mi][ni] = __builtin_amdgcn_mfma_f32_16x16x32_bf16(af[mi], bfr[ni], acc[mi][ni], 0, 0, 0);
    }
    __syncthreads();
  }

  const int rbase = (lane >> 4) << 2;
  const int cbase = lane & 15;
  float bc[4];
#pragma unroll
  for (int ni = 0; ni < 4; ++ni) bc[ni] = bcP[n0 + wn * 64 + ni * 16 + cbase];
#pragma unroll
  for (int mi = 0; mi < 4; ++mi) {
#pragma unroll
    for (int ni = 0; ni < 4; ++ni) {
      int gc = n0 + wn * 64 + ni * 16 + cbase;
#pragma unroll
      for (int r = 0; r < 4; ++r) {
        int gm = m0 + wm * 64 + mi * 16 + rbase + r;
        GXc[(size_t)gm * G4_ + gc] = f2bf(acc[mi][ni][r] + bc[ni]);
      }
    }
  }
}

// ---------- persistent recurrent kernel: all 64 steps, NO fences.
// 512 threads/block (8 waves of 16 rows) for 16 waves/CU TLP; tile still 128x64.
// h via write-through stores + per-step fresh ring buffer. Per-group flag barrier.
// GX loads NT; GX(t+1) issued in epilogue after h stores (vmcnt(2) drains stores only).
__global__ void __launch_bounds__(512, 4) rec_kernel(
    const u16* __restrict__ h0slot, u16* __restrict__ hring,
    const u16* __restrict__ WhhP, const u16* __restrict__ GXall,
    const float* __restrict__ c0, float* __restrict__ partAll,
    const float* __restrict__ Wout, u32* __restrict__ flags) {
  __shared__ char smem[81920];  // A dbuf 2x16K | B dbuf 2x8K @32768 | GX dbuf 2x16K @49152
  const int tid = threadIdx.x;
  const int lane = tid & 63;
  const int qm = tid >> 6;  // wave = m-slice [0,8), 16 rows each
  const int hbid = blockIdx.x;
  const int L = (hbid & 7) * 64 + (hbid >> 3);  // XCD swizzle: W n-slice per XCD
  const int bx = L >> 3;   // [0,64): n-tile
  const int by = L & 7;    // [0,8): m-tile
  const int n0 = bx * 64;
  const int m0 = by * 128;

  int offA[2], offGX[2], betaS[2];
  int offB, betaB;
#pragma unroll
  for (int s = 0; s < 2; ++s) {
    int beta = (s * 512 + tid) * 16;             // 0..16K
    int row = beta >> 7;
    int colu = (beta & 127) ^ ((row & 7) << 4);
    offA[s] = (m0 + row) * 1024 + (colu >> 1);
    offGX[s] = (m0 + row) * G4_ + n0 + (colu >> 1);
    betaS[s] = beta;
  }
  {
    int beta = tid * 16;                         // 0..8K
    int row = beta >> 7;
    int colu = (beta & 127) ^ ((row & 7) << 4);
    offB = (n0 + row) * 1024 + (colu >> 1);
    betaB = beta;
  }

  const int rsel = lane & 15;
  const int ksel = (lane >> 4) << 4;
  const int rbase = (lane >> 4) << 2;
  const int cbase = lane & 15;
  const int j = bx * 16 + cbase;
  const float w0 = Wout[j], w1 = Wout[1024 + j];

  // cell state lives in registers for the whole sequence (4 rows per thread)
  float creg[4];
#pragma unroll
  for (int r = 0; r < 4; ++r)
    creg[r] = c0[(size_t)(m0 + qm * 16 + rbase + r) * H_ + j];

  // GX(0) -> gx buffer 0 (NT; absorbed by kt0's vmcnt(3) of step 0)
#pragma unroll
  for (int s = 0; s < 2; ++s) gload16_nt(GXall + offGX[s], smem + 49152 + betaS[s]);

#pragma unroll 1
  for (int t = 0; t < T_; ++t) {
    // B(Whh) tile 0 -> buffer 0: barrier-independent, issue before the poll.
    gload16(WhhP + offB, smem + 32768 + betaB);

    if (t) {
      // group barrier: wait for the 64 same-by blocks (they wrote our h rows, step t-1)
      if (tid < 64) {
        const u32* fg = flags + (size_t)(t - 1) * NBLK_ + by * 64;
        int guard = 0;
        while (true) {
          u32 v = __hip_atomic_load(fg + tid, __ATOMIC_RELAXED, __HIP_MEMORY_SCOPE_AGENT);
          if (__all(v != 0)) break;
          __builtin_amdgcn_s_sleep(4);
          if (++guard > (1 << 18)) break;  // bounded: fail loud, never hang
        }
      }
      __syncthreads();  // no acquire fence: h buffer fresh, L2 never cached it
    }

    // h ring: step t reads hring[t-1] (t=0 -> h0slot), writes hring[t]
    const u16* hbR = t ? (hring + (size_t)(t - 1) * HB_) : h0slot;
    u16* hbW = hring + (size_t)t * HB_;

    // A(h) tile 0 (needs the barrier)
#pragma unroll
    for (int s = 0; s < 2; ++s) gload16(hbR + offA[s], smem + betaS[s]);

    f32x4 acc[4] = {};
#pragma unroll
    for (int kt = 0; kt < 16; ++kt) {
      const int cur = kt & 1;
      const int abase = cur * 16384;
      const int bbase = 32768 + cur * 8192;
      if (kt < 15) {
        const int nab = (cur ^ 1) * 16384;
        const int nbb = 32768 + (cur ^ 1) * 8192;
        const int kadv = (kt + 1) * 64;
#pragma unroll
        for (int s = 0; s < 2; ++s) gload16(hbR + offA[s] + kadv, smem + nab + betaS[s]);
        gload16(WhhP + offB + kadv, smem + nbb + betaB);
        // steady: queue = [3 tile_kt, 3 tile_kt+1] -> vmcnt(3) drains tile kt.
        // kt0: queue = [2 GX, 1 B0, 2 A0, 3 tile1] -> vmcnt(3) drains GX+B0+A0.
        asm volatile("s_waitcnt vmcnt(3)" ::: "memory");
      } else {
        asm volatile("s_waitcnt vmcnt(0)" ::: "memory");
      }
      __builtin_amdgcn_s_barrier();
      __builtin_amdgcn_sched_barrier(0);
#pragma unroll
      for (int kk = 0; kk < 2; ++kk) {
        const int colb = kk * 64 + ksel;
        bf16x8 af, bfr[4];
        {
          int row = qm * 16 + rsel;
          af = *(const bf16x8*)(smem + abase + row * 128 + (colb ^ ((row & 7) << 4)));
        }
#pragma unroll
        for (int ni = 0; ni < 4; ++ni) {
          int row = ni * 16 + rsel;
          bfr[ni] = *(const bf16x8*)(smem + bbase + row * 128 + (colb ^ ((row & 7) << 4)));
        }
#pragma unroll
        for (int ni = 0; ni < 4; ++ni)
          acc[ni] = __builtin_amdgcn_mfma_f32_16x16x32_bf16(af, bfr[ni], acc[ni], 0, 0, 0);
      }
      __builtin_amdgcn_s_barrier();
      __builtin_amdgcn_sched_barrier(0);
    }

    // epilogue pass 1: gates = acc + GX(LDS); cell on register c; write-through h
    const char* lsGX = smem + 49152 + (t & 1) * 16384;
#pragma unroll
    for (int r = 0; r < 4; ++r) {
      int grow = qm * 16 + rbase + r;  // row within 128-tile
      int b = m0 + grow;
      int gxswz = (grow & 7) << 4;
      float gx0 = __uint_as_float(
          (u32)*(const u16*)(lsGX + ((grow << 7) | ((cbase << 1) ^ gxswz))) << 16);
      float gx1 = __uint_as_float(
          (u32)*(const u16*)(lsGX + ((grow << 7) | ((((16 + cbase) << 1)) ^ gxswz))) << 16);
      float gx2 = __uint_as_float(
          (u32)*(const u16*)(lsGX + ((grow << 7) | ((((32 + cbase) << 1)) ^ gxswz))) << 16);
      float gx3 = __uint_as_float(
          (u32)*(const u16*)(lsGX + ((grow << 7) | ((((48 + cbase) << 1)) ^ gxswz))) << 16);
      float gi = acc[0][r] + gx0;
      float gf = acc[1][r] + gx1;
      float gg = acc[2][r] + gx2;
      float go = acc[3][r] + gx3;
      float c2 = fsig(gf) * creg[r] + fsig(gi) * ftanh(gg);
      float h2 = fsig(go) * ftanh(c2);
      creg[r] = c2;
      store_wt16(hbW + (size_t)b * H_ + j, f2bf(h2));
    }

    // GX(t+1) prefetch AFTER the stores (NT): newest in queue -> vmcnt(2) below
    // drains exactly the 4 h stores and leaves GX in flight.
    if (t + 1 < T_) {
      const u16* GXn = GXall + (size_t)(t + 1) * B_ * G4_;
      const int gxb = 49152 + ((t + 1) & 1) * 16384;
#pragma unroll
      for (int s = 0; s < 2; ++s) gload16_nt(GXn + offGX[s], smem + gxb + betaS[s]);
      asm volatile("s_waitcnt vmcnt(2)" ::: "memory");
    } else {
      asm volatile("s_waitcnt vmcnt(0)" ::: "memory");
    }
    __syncthreads();
    if (tid == 0)
      __hip_atomic_store(flags + (size_t)t * NBLK_ + by * 64 + bx, 1u,
                         __ATOMIC_RELAXED, __HIP_MEMORY_SCOPE_AGENT);

    // epilogue pass 2 (off critical path): head partials from creg
    float* partW = partAll + (size_t)t * PARTSZ_;
#pragma unroll
    for (int r = 0; r < 4; ++r) {
      int b = m0 + qm * 16 + rbase + r;
      float p0 = creg[r] * w0, p1 = creg[r] * w1;
#pragma unroll
      for (int off = 1; off < 16; off <<= 1) {
        p0 += __shfl_xor(p0, off);
        p1 += __shfl_xor(p1, off);
      }
      if (cbase == 0) {
        partW[(b << 7) + bx] = p0;
        partW[(b << 7) + 64 + bx] = p1;
      }
    }
  }
}

// ---------- final: reduce ALL steps' partials -> out[t] log-softmax; t=63 also raw out_final
__global__ void final_kernel(const float* __restrict__ partAll, const float* __restrict__ bout,
                             float* __restrict__ out) {
  int gid = blockIdx.x * 256 + threadIdx.x;  // 131072 = 64 t x 1024 b x 2 cls
  int t = gid >> 11;
  int r = gid & 2047;
  int b = r >> 1, cls = r & 1;
  const float4* pp = (const float4*)(partAll + (size_t)t * PARTSZ_ + (b << 7) + cls * 64);
  float4 sv = {0.f, 0.f, 0.f, 0.f};
#pragma unroll
  for (int q = 0; q < 16; ++q) {
    float4 v = pp[q];
    sv.x += v.x; sv.y += v.y; sv.z += v.z; sv.w += v.w;
  }
  float l = sv.x + sv.y + sv.z + sv.w + bout[cls];
  float other = __shfl_xor(l, 1);
  float m = fmaxf(l, other);
  float ls = m + __logf(__expf(l - m) + __expf(other - m));
  out[(size_t)t * (B_ * 2) + b * 2 + cls] = l - ls;
  if (t == 63) out[(size_t)T_ * (B_ * 2) + b * 2 + cls] = l;  // out_final raw
}

extern "C" void kernel_launch(void* const* d_in, const int* in_sizes, int n_in,
                              void* d_out, int out_size, void* d_ws, size_t ws_size,
                              hipStream_t stream) {
  const int* x      = (const int*)d_in[0];
  const float* emb  = (const float*)d_in[1];
  const float* W_ih = (const float*)d_in[2];
  const float* W_hh = (const float*)d_in[3];
  const float* b_ih = (const float*)d_in[4];
  const float* b_hh = (const float*)d_in[5];
  const float* W_out = (const float*)d_in[6];
  const float* b_out = (const float*)d_in[7];
  const float* h0   = (const float*)d_in[8];
  const float* c0   = (const float*)d_in[9];
  float* out = (float*)d_out;

  // workspace (~691 MB): XEall region is DEAD after xproj -> reused as the h ring.
  char* w = (char*)d_ws;
  u16* WihP = (u16*)w;   w += (size_t)G4_ * H_ * 2;             // 8 MB
  u16* WhhP = (u16*)w;   w += (size_t)G4_ * H_ * 2;             // 8 MB
  u16* XEall = (u16*)w;  w += (size_t)T_ * HB_ * 2;             // 128 MB (= hring[1..64])
  u16* GXall = (u16*)w;  w += (size_t)T_ * B_ * G4_ * 2;        // 512 MB
  u16* h0slot = (u16*)w; w += (size_t)HB_ * 2;                  // 2 MB (hring[0])
  float* bcP = (float*)w;     w += (size_t)G4_ * 4;
  float* partAll = (float*)w; w += (size_t)T_ * PARTSZ_ * 4;    // 32 MB
  u32* flags = (u32*)w;       w += (size_t)T_ * NBLK_ * 4;      // 128 KB

  prep_kernel<<<5153, 256, 0, stream>>>(W_ih, W_hh, b_ih, b_hh, h0,
                                        WihP, WhhP, bcP, h0slot, flags);
  gather_kernel<<<dim3(B_, T_), 256, 0, stream>>>(x, emb, XEall);
  for (int ch = 0; ch < T_ / CHUNK_; ++ch) {
    xproj_kernel<<<4096, 256, 0, stream>>>(XEall + (size_t)ch * CHUNK_ * HB_, WihP, bcP,
                                           GXall + (size_t)ch * CHUNK_ * B_ * G4_);
  }
  rec_kernel<<<NBLK_, 512, 0, stream>>>(h0slot, XEall /*hring[1..]*/, WhhP, GXall, c0,
                                        partAll, W_out, flags);
  final_kernel<<<512, 256, 0, stream>>>(partAll, b_out, out);
}